// Round 17
// baseline (1325.378 us; speedup 1.0000x reference)
//
#include <hip/hip_runtime.h>
#include <hip/hip_bf16.h>
#include <stdint.h>
#include <stddef.h>

#define LAYERS 8
#define NCH 256
#define NMEL 640
#define NBATCH 16
#define SEQT 4096
#define BTROWS (NBATCH * SEQT)   // 65536
#define PADT 128
#define TPAD (SEQT + 2 * PADT)   // 4352
#define KX 1408                  // 3*256 + 640

// NC8 layouts (all bf16, inner dim = 8 channels/k):
//  hpad : [b][32 cc][TPAD t][8]
//  spect: [b][80 cc][4096 t][8]
//  acts : [b][32 cc][4096 t][8]
//  wx   : [layer][44 kt][4 kc][512 n][8]
//  wr   : [layer][ 8 kt][4 kc][512 n][8]
//  skip : [m][256]  (row-major, feeds end_kernel)

typedef __hip_bfloat16 bf16;
typedef __attribute__((ext_vector_type(8))) short short8;
typedef __attribute__((ext_vector_type(4))) float f32x4;

__device__ __forceinline__ void g2l16(const void* g, void* l) {
  __builtin_amdgcn_global_load_lds(
      (const __attribute__((address_space(1))) unsigned int*)g,
      (__attribute__((address_space(3))) unsigned int*)l, 16, 0, 0);
}

#define VM6()   asm volatile("s_waitcnt vmcnt(6)"  ::: "memory")
#define VM5()   asm volatile("s_waitcnt vmcnt(5)"  ::: "memory")
#define VM0()   asm volatile("s_waitcnt vmcnt(0)"  ::: "memory")
#define LGKM0() asm volatile("s_waitcnt lgkmcnt(0)" ::: "memory")
#define SB0()   __builtin_amdgcn_sched_barrier(0)
#define BAR()   __builtin_amdgcn_s_barrier()

__device__ __forceinline__ float fsigmoid(float x) { return 1.f / (1.f + __expf(-x)); }
__device__ __forceinline__ float ftanh_(float x) { return 1.f - 2.f / (__expf(2.f * x) + 1.f); }
__device__ __forceinline__ float bf2f(unsigned short u) {
  unsigned x = ((unsigned)u) << 16; float f; __builtin_memcpy(&f, &x, 4); return f;
}
__device__ __forceinline__ short f2bf_s(float x) {
  bf16 v = __float2bfloat16(x); short s; __builtin_memcpy(&s, &v, 2); return s;
}

// ---------------------------------------------------------------------------
// GEMM1 (HYBRID): x = [h(t-d);h(t);h(t+d);spect] @ Wstack^T ;
// acts = tanh(x1)*sig(x2). Block 4 waves (2m x 2n) = 128 rows x (64t + 64s),
// acc 64 AGPR (3 waves/SIMD). A staged in LDS ring-2 8KB slots; B-fragments
// loaded DIRECTLY global->regs (weights L2-resident; 256B-segment coalesced).
// Per-chunk LDS traffic 24KB (was 48KB). Sync (R16-proven skeleton):
//   B-regs(kt) ; stage A(kt+1) ; vmcnt(6) ; bar ; 4 ds_reads ; lgkm0 ; bar ;
//   MFMA (compiler scoreboards B regs).
// vmcnt(6) retires stage(kt): outstanding newest = B(kt)4 + stage(kt+1)2.
// ---------------------------------------------------------------------------
__global__ __launch_bounds__(256, 3) void gemm1_kernel(
    const bf16* __restrict__ hpad, const bf16* __restrict__ spect,
    const bf16* __restrict__ wx,   // this layer: [44][4][512][8]
    const float* __restrict__ xb,  // [512] combined in_b + cond_b
    bf16* __restrict__ acts, int dil)
{
  // slot (shorts): A [4 kc][128 t][8] = 4096 -> ring-2 = 16 KB total
  __shared__ alignas(16) short lds[2 * 4096];

  const int tid  = threadIdx.x;
  const int lane = tid & 63;
  const int wid  = tid >> 6;
  const int wm   = wid >> 1;          // 0..1
  const int wn   = wid & 1;           // 0..1

  const int bx  = blockIdx.x;                      // 512 m-tiles
  const int swz = ((bx & 7) << 6) | (bx >> 3);     // bijective on [0,512)
  const int m0 = swz * 128;
  const int c0 = blockIdx.y * 64;     // tanh channel tile: 0/64/128/192
  const int b  = m0 >> 12;            // tile fully inside one batch
  const int t0 = m0 & (SEQT - 1);

  const f32x4 fzero = {0.f, 0.f, 0.f, 0.f};
  f32x4 acc1[4][2], acc2[4][2];
#pragma unroll
  for (int i = 0; i < 4; ++i)
#pragma unroll
    for (int j = 0; j < 2; ++j) { acc1[i][j] = fzero; acc2[i][j] = fzero; }

  const int tA  = tid & 127;
  const int ccA = tid >> 7;           // 0..1 -> stages cc=ccA, ccA+2

  const bf16* pAh = hpad  + (((size_t)b * 32 + ccA) * TPAD + PADT + t0 + tA) * 8;
  const bf16* pAs = spect + (((size_t)b * 80 + ccA) * 4096 + t0 + tA) * 8;
  const ptrdiff_t dil8 = (ptrdiff_t)dil * 8;

  const int rl = lane & 15;           // fr: col-in-16
  const int kc = lane >> 4;           // fk: k-slice plane 0..3

  // per-lane B fragment base (chunk 0, frag j at +j*128, sigmoid at +2048)
  const bf16* pBg = wx + ((size_t)(kc * 512) + c0 + wn * 32 + rl) * 8;

  auto stage = [&](int kt) {
    short* base = lds + (kt & 1) * 4096;
    const bf16* a0;
    ptrdiff_t astep;
    if (kt < 24) {
      const int tap = kt >> 3;                       // 0,1,2
      a0 = pAh + (ptrdiff_t)((kt & 7) * 4) * (TPAD * 8) + (ptrdiff_t)(tap - 1) * dil8;
      astep = (ptrdiff_t)2 * TPAD * 8;
    } else {
      a0 = pAs + (ptrdiff_t)(kt - 24) * 131072;      // 4*4096*8
      astep = (ptrdiff_t)2 * 4096 * 8;
    }
    g2l16(a0,         base + (ccA * 128 + tA) * 8);
    g2l16(a0 + astep, base + ((ccA + 2) * 128 + tA) * 8);
  };

  stage(0);                            // PROLOGUE
  for (int kt = 0; kt < 44; ++kt) {
    // B fragments for this chunk: 4 global reg-loads (L2-hot weights)
    const bf16* wb = pBg + (ptrdiff_t)kt * 16384;   // 4*512*8
    short8 bfa[2], bfb[2];
#pragma unroll
    for (int j = 0; j < 2; ++j) {
      bfa[j] = *(const short8*)(wb + j * 128);
      bfb[j] = *(const short8*)(wb + 2048 + j * 128);   // +256 cols (sigmoid)
    }

    if (kt < 43) { stage(kt + 1); VM6(); }
    else         { VM0(); }
    BAR();                             // slot kt&1 fully staged (all waves)

    const short* cur = lds + (kt & 1) * 4096;
    short8 af[4];
#pragma unroll
    for (int f = 0; f < 4; ++f)
      af[f] = *(const short8*)(cur + (kc * 128 + wm * 64 + f * 16 + rl) * 8);
    LGKM0();
    SB0();
    BAR();                             // all reads of slot kt&1 retired
    __builtin_amdgcn_s_setprio(1);
#pragma unroll
    for (int i = 0; i < 4; ++i)
#pragma unroll
      for (int j = 0; j < 2; ++j) {
        acc1[i][j] = __builtin_amdgcn_mfma_f32_16x16x32_bf16(af[i], bfa[j], acc1[i][j], 0, 0, 0);
        acc2[i][j] = __builtin_amdgcn_mfma_f32_16x16x32_bf16(af[i], bfb[j], acc2[i][j], 0, 0, 0);
      }
    __builtin_amdgcn_s_setprio(0);
  }

  // ---- epilogue: gate -> LDS bounce [8 cc'][128 t][8] (16 KB) -> coalesced
  short* obuf = lds;
  const int rl2 = lane & 15;
  const int ro  = (lane >> 4) * 4;
#pragma unroll
  for (int i = 0; i < 4; ++i) {
#pragma unroll
    for (int j = 0; j < 2; ++j) {
      const int lc = wn * 32 + j * 16 + rl2;         // local tanh ch 0..63
      const float bx1 = xb[c0 + lc];
      const float bx2 = xb[c0 + lc + 256];
#pragma unroll
      for (int r = 0; r < 4; ++r) {
        const int t = wm * 64 + i * 16 + ro + r;     // 0..127
        const float x1 = acc1[i][j][r] + bx1;
        const float x2 = acc2[i][j][r] + bx2;
        obuf[((lc >> 3) * 128 + t) * 8 + (lc & 7)] = f2bf_s(ftanh_(x1) * fsigmoid(x2));
      }
    }
  }
  __syncthreads();
  const int tt = tid & 127;
  const int c2 = tid >> 7;            // 0..1
  short* ag = (short*)acts;
#pragma unroll
  for (int q = 0; q < 4; ++q) {
    const int ccp = c2 * 4 + q;       // 0..7
    const short8 v = *(const short8*)(obuf + (ccp * 128 + tt) * 8);
    *(short8*)(ag + ((size_t)(b * 32 + (c0 >> 3) + ccp) * 4096 + t0 + tt) * 8) = v;
  }
}

// ---------------------------------------------------------------------------
// GEMM2: rs = acts @ Wr^T (+rb); blockIdx.y==0 -> h += rs ; ==1 -> skip += rs
// R13 structure (64 rows x 256 cols, acc 64 AGPR) + R15 coalesced epilogues.
// ---------------------------------------------------------------------------
__global__ __launch_bounds__(256, 3) void gemm2_kernel(
    const bf16* __restrict__ acts, const bf16* __restrict__ wr,  // [8][4][512][8]
    const float* __restrict__ rb, bf16* __restrict__ hpad,
    bf16* __restrict__ skip, const int first)
{
  // slot (shorts): A [4 kc][64 t][8]=2048, B [4 kc][256 n][8]=8192
  __shared__ alignas(16) short lds[2 * 10240];   // 40 KB (obuf needs 32 KB)

  const int tid  = threadIdx.x;
  const int lane = tid & 63;
  const int wid  = tid >> 6;
  const int wm   = wid >> 1;          // 0..1
  const int wn   = wid & 1;           // 0..1

  const int bx  = blockIdx.x;
  const int swz = ((bx & 7) << 7) | (bx >> 3);     // bijective on [0,1024)
  const int m0 = swz * 64;
  const int n0 = blockIdx.y * 256;    // 0 (h-update) or 256 (skip)
  const int b  = m0 >> 12;
  const int t0 = m0 & (SEQT - 1);

  const f32x4 fzero = {0.f, 0.f, 0.f, 0.f};
  f32x4 acc[2][8];
#pragma unroll
  for (int i = 0; i < 2; ++i)
#pragma unroll
    for (int j = 0; j < 8; ++j) acc[i][j] = fzero;

  const int tA  = tid & 63;
  const int ccA = tid >> 6;           // 0..3

  const bf16* pA = acts + (((size_t)b * 32 + ccA) * 4096 + t0 + tA) * 8;
  const bf16* pB = wr + ((size_t)n0 + tid) * 8;    // col n0+tid, all 4 kc

  auto stage = [&](int kt) {
    short* base = lds + (kt & 1) * 10240;
    const bf16* a0 = pA + (ptrdiff_t)kt * 131072;  // 4*4096*8
    const bf16* w0 = pB + (ptrdiff_t)kt * 16384;   // 4*512*8
    g2l16(a0, base + (ccA * 64 + tA) * 8);
#pragma unroll
    for (int kcq = 0; kcq < 4; ++kcq)
      g2l16(w0 + kcq * 4096, base + 2048 + (kcq * 256 + tid) * 8);
  };

  const int rl = lane & 15;
  const int kc = lane >> 4;

  stage(0);                            // PROLOGUE
  for (int kt = 0; kt < 8; ++kt) {
    if (kt < 7) { stage(kt + 1); VM5(); }
    else        { VM0(); }
    BAR();

    const short* cur = lds + (kt & 1) * 10240;
    short8 af[2], bfr[8];
#pragma unroll
    for (int f = 0; f < 2; ++f)
      af[f] = *(const short8*)(cur + (kc * 64 + wm * 32 + f * 16 + rl) * 8);
#pragma unroll
    for (int j = 0; j < 8; ++j)
      bfr[j] = *(const short8*)(cur + 2048 + (kc * 256 + wn * 128 + j * 16 + rl) * 8);
    LGKM0();
    SB0();
    BAR();
    __builtin_amdgcn_s_setprio(1);
#pragma unroll
    for (int i = 0; i < 2; ++i)
#pragma unroll
      for (int j = 0; j < 8; ++j)
        acc[i][j] = __builtin_amdgcn_mfma_f32_16x16x32_bf16(af[i], bfr[j], acc[i][j], 0, 0, 0);
    __builtin_amdgcn_s_setprio(0);
  }

  // ---- epilogue: rs+bias -> LDS bounce -> coalesced RMW
  short* obuf = lds;
  const int rl2 = lane & 15;
  const int ro  = (lane >> 4) * 4;
  if (n0 == 0) {
    // h-update: obuf NC8 [32 cc][64 t][8] = 32 KB
#pragma unroll
    for (int i = 0; i < 2; ++i) {
#pragma unroll
      for (int j = 0; j < 8; ++j) {
        const int n = wn * 128 + j * 16 + rl2;       // 0..255
        const float bias = rb[n];
#pragma unroll
        for (int r = 0; r < 4; ++r) {
          const int t = wm * 32 + i * 16 + ro + r;
          obuf[((n >> 3) * 64 + t) * 8 + (n & 7)] = f2bf_s(acc[i][j][r] + bias);
        }
      }
    }
    __syncthreads();
    const int tt = tid & 63;
    const int c4 = tid >> 6;
    short* hg = (short*)hpad;
#pragma unroll
    for (int q = 0; q < 8; ++q) {
      const int cc = c4 * 8 + q;                     // 0..31
      const size_t gi = (((size_t)b * 32 + cc) * TPAD + PADT + t0 + tt) * 8;
      short8 hv = *(const short8*)(hg + gi);
      const short8 rv = *(const short8*)(obuf + (cc * 64 + tt) * 8);
      short8 ov;
#pragma unroll
      for (int w = 0; w < 8; ++w)
        ov[w] = f2bf_s(bf2f((unsigned short)hv[w]) + bf2f((unsigned short)rv[w]));
      *(short8*)(hg + gi) = ov;
    }
  } else {
    // skip: obuf row-major [64 t][256 n] = 32 KB
#pragma unroll
    for (int i = 0; i < 2; ++i) {
#pragma unroll
      for (int j = 0; j < 8; ++j) {
        const int n = wn * 128 + j * 16 + rl2;       // 0..255
        const float bias = rb[256 + n];
#pragma unroll
        for (int r = 0; r < 4; ++r) {
          const int t = wm * 32 + i * 16 + ro + r;
          obuf[t * 256 + n] = f2bf_s(acc[i][j][r] + bias);
        }
      }
    }
    __syncthreads();
    short* sg = (short*)skip;
#pragma unroll
    for (int q = 0; q < 8; ++q) {
      const int idx = q * 256 + tid;                 // 0..2047 chunks
      const int t  = idx >> 5;
      const int nc = idx & 31;
      const size_t gi = ((size_t)(b * SEQT + t0 + t)) * NCH + nc * 8;
      const short8 rv = *(const short8*)(obuf + t * 256 + nc * 8);
      if (first) {
        *(short8*)(sg + gi) = rv;
      } else {
        short8 sv = *(const short8*)(sg + gi);
        short8 ov;
#pragma unroll
        for (int w = 0; w < 8; ++w)
          ov[w] = f2bf_s(bf2f((unsigned short)sv[w]) + bf2f((unsigned short)rv[w]));
        *(short8*)(sg + gi) = ov;
      }
    }
  }
}

// ---------------------------------------------------------------------------
// aux kernels
// ---------------------------------------------------------------------------
__global__ void start_kernel(const float* __restrict__ audio, const float* __restrict__ sw,
                             const float* __restrict__ sb, bf16* __restrict__ hpad)
{
  const int idx = blockIdx.x * 256 + threadIdx.x;   // < 16777216
  const int w  = idx & 7;
  const int t  = (idx >> 3) & 4095;
  const int cc = (idx >> 15) & 31;
  const int b  = idx >> 20;
  const int c  = cc * 8 + w;
  const float* a = audio + ((size_t)(b * SEQT + t)) * 4;
  float v = sb[c] + a[0] * sw[c] + a[1] * sw[256 + c] + a[2] * sw[512 + c] + a[3] * sw[768 + c];
  hpad[(((size_t)b * 32 + cc) * TPAD + PADT + t) * 8 + w] = __float2bfloat16(v);
}

__global__ void cvt_spect_kernel(const float* __restrict__ s, bf16* __restrict__ d)
{
  const size_t idx = (size_t)blockIdx.x * 256 + threadIdx.x;  // < 41943040
  const int w  = (int)(idx & 7);
  const int t  = (int)((idx >> 3) & 4095);
  const unsigned q = (unsigned)(idx >> 15);     // b*80 + cc
  const int b  = q / 80;
  const int cc = q % 80;
  const int c  = cc * 8 + w;
  d[idx] = __float2bfloat16(s[((size_t)(b * SEQT + t)) * NMEL + c]);
}

__global__ void prep_wx_kernel(const float* __restrict__ in_w, const float* __restrict__ cond_w,
                               bf16* __restrict__ wx)
{
  const size_t idx = (size_t)blockIdx.x * 256 + threadIdx.x;
  if (idx >= (size_t)LAYERS * 44 * 4 * 512 * 8) return;
  const int w   = (int)(idx & 7);
  const int n   = (int)((idx >> 3) & 511);
  const int kc  = (int)((idx >> 12) & 3);
  const unsigned ktp = (unsigned)(idx >> 14);   // i*44 + kt
  const int i  = ktp / 44;
  const int kt = ktp % 44;
  const int k  = kt * 32 + kc * 8 + w;
  float v;
  if (k < 768) {
    const int tap = k >> 8;
    const int c   = k & 255;
    v = in_w[(size_t)(((i * 3 + tap) << 8) + c) * 512 + n];
  } else {
    v = cond_w[((size_t)i * NMEL + (k - 768)) * 512 + n];
  }
  wx[idx] = __float2bfloat16(v);
}

__global__ void prep_wr_kernel(const float* __restrict__ rs_w, const float* __restrict__ rs_w_last,
                               bf16* __restrict__ wr)
{
  const int idx = blockIdx.x * 256 + threadIdx.x;   // < 1048576
  const int w  = idx & 7;
  const int n  = (idx >> 3) & 511;
  const int kc = (idx >> 12) & 3;
  const int kt = (idx >> 14) & 7;
  const int i  = idx >> 17;
  const int k  = kt * 32 + kc * 8 + w;              // [0,256)
  float v;
  if (i < LAYERS - 1) v = rs_w[(size_t)((i << 8) + k) * 512 + n];
  else                v = (n >= 256) ? rs_w_last[(k << 8) + (n - 256)] : 0.f;
  wr[idx] = __float2bfloat16(v);
}

__global__ void prep_bias_kernel(const float* __restrict__ in_b, const float* __restrict__ cond_b,
                                 const float* __restrict__ rs_b, const float* __restrict__ rs_b_last,
                                 float* __restrict__ xb, float* __restrict__ rb)
{
  const int idx = blockIdx.x * 256 + threadIdx.x;   // < 4096
  if (idx >= LAYERS * 512) return;
  const int i = idx >> 9;
  const int n = idx & 511;
  xb[idx] = in_b[idx] + cond_b[idx];
  rb[idx] = (i < LAYERS - 1) ? rs_b[idx] : ((n >= 256) ? rs_b_last[n - 256] : 0.f);
}

__global__ void end_kernel(const bf16* __restrict__ skip, const float* __restrict__ ew,
                           const float* __restrict__ eb, float* __restrict__ out)
{
  const int idx = blockIdx.x * 256 + threadIdx.x;   // < 524288
  const int m = idx >> 3;
  const int j = idx & 7;
  const bf16* srow = skip + (size_t)m * NCH;
  float s = eb[j];
#pragma unroll 4
  for (int c8 = 0; c8 < NCH / 8; ++c8) {
    short8 v = *(const short8*)(srow + c8 * 8);
#pragma unroll
    for (int w = 0; w < 8; ++w)
      s += bf2f((unsigned short)v[w]) * ew[(c8 * 8 + w) * 8 + j];
  }
  out[idx] = s;
}

// ---------------------------------------------------------------------------
extern "C" void kernel_launch(void* const* d_in, const int* in_sizes, int n_in,
                              void* d_out, int out_size, void* d_ws, size_t ws_size,
                              hipStream_t stream)
{
  const float* audio     = (const float*)d_in[0];
  const float* spect     = (const float*)d_in[1];
  const float* start_w   = (const float*)d_in[2];
  const float* start_b   = (const float*)d_in[3];
  const float* in_w      = (const float*)d_in[4];
  const float* in_b      = (const float*)d_in[5];
  const float* cond_w    = (const float*)d_in[6];
  const float* cond_b    = (const float*)d_in[7];
  const float* rs_w      = (const float*)d_in[8];
  const float* rs_b      = (const float*)d_in[9];
  const float* rs_w_last = (const float*)d_in[10];
  const float* rs_b_last = (const float*)d_in[11];
  const float* end_w     = (const float*)d_in[12];
  const float* end_b     = (const float*)d_in[13];
  float* out = (float*)d_out;

  char* p = (char*)d_ws;
  bf16* spect_bf = (bf16*)p;  p += (size_t)BTROWS * NMEL * 2;          // 83.9 MB
  bf16* hpad     = (bf16*)p;  p += (size_t)NBATCH * 32 * TPAD * 8 * 2; // 35.7 MB
  bf16* actsb    = (bf16*)p;  p += (size_t)BTROWS * NCH * 2;           // 33.6 MB
  bf16* skip     = (bf16*)p;  p += (size_t)BTROWS * NCH * 2;           // 33.6 MB
  bf16* wx       = (bf16*)p;  p += (size_t)LAYERS * 512 * KX * 2;      // 11.5 MB
  bf16* wr       = (bf16*)p;  p += (size_t)LAYERS * 512 * 256 * 2;     //  2.1 MB
  float* xb      = (float*)p; p += (size_t)LAYERS * 512 * 4;
  float* rb      = (float*)p; p += (size_t)LAYERS * 512 * 4;
  if ((size_t)(p - (char*)d_ws) > ws_size) return;  // insufficient workspace

  hipMemsetAsync(hpad, 0, (size_t)NBATCH * 32 * TPAD * 8 * 2, stream);
  prep_wx_kernel<<<(LAYERS * 512 * KX + 255) / 256, 256, 0, stream>>>(in_w, cond_w, wx);
  prep_wr_kernel<<<(LAYERS * 512 * 256) / 256, 256, 0, stream>>>(rs_w, rs_w_last, wr);
  prep_bias_kernel<<<16, 256, 0, stream>>>(in_b, cond_b, rs_b, rs_b_last, xb, rb);
  cvt_spect_kernel<<<(BTROWS * NMEL) / 256, 256, 0, stream>>>(spect, spect_bf);
  start_kernel<<<(BTROWS * NCH) / 256, 256, 0, stream>>>(audio, start_w, start_b, hpad);

  for (int i = 0; i < LAYERS; ++i) {
    gemm1_kernel<<<dim3(512, 4), 256, 0, stream>>>(hpad, spect_bf, wx + (size_t)i * 44 * 4 * 512 * 8,
                                                   xb + i * 512, actsb, 1 << i);
    gemm2_kernel<<<dim3(1024, 2), 256, 0, stream>>>(actsb, wr + (size_t)i * 8 * 4 * 512 * 8,
                                                    rb + i * 512, hpad, skip, i == 0 ? 1 : 0);
  }
  end_kernel<<<(BTROWS * 8) / 256, 256, 0, stream>>>(skip, end_w, end_b, out);
}

// Round 18
// 1309.240 us; speedup vs baseline: 1.0123x; 1.0123x over previous
//
#include <hip/hip_runtime.h>
#include <hip/hip_bf16.h>
#include <stdint.h>
#include <stddef.h>

#define LAYERS 8
#define NCH 256
#define NMEL 640
#define NBATCH 16
#define SEQT 4096
#define BTROWS (NBATCH * SEQT)   // 65536
#define PADT 128
#define TPAD (SEQT + 2 * PADT)   // 4352
#define KX 1408                  // 3*256 + 640

// NC8 layouts (all bf16, inner dim = 8 channels/k):
//  hpad : [b][32 cc][TPAD t][8]
//  spect: [b][80 cc][4096 t][8]
//  acts : [b][32 cc][4096 t][8]
//  wx   : [layer][44 kt][4 kc][512 n][8]
//  wr   : [layer][ 8 kt][4 kc][512 n][8]
//  skip : [m][256]  (row-major, feeds end_kernel)

typedef __hip_bfloat16 bf16;
typedef __attribute__((ext_vector_type(8))) short short8;
typedef __attribute__((ext_vector_type(4))) float f32x4;
typedef __attribute__((ext_vector_type(16))) float f32x16;

__device__ __forceinline__ void g2l16(const void* g, void* l) {
  __builtin_amdgcn_global_load_lds(
      (const __attribute__((address_space(1))) unsigned int*)g,
      (__attribute__((address_space(3))) unsigned int*)l, 16, 0, 0);
}

#define VM4()   asm volatile("s_waitcnt vmcnt(4)"  ::: "memory")
#define VM5()   asm volatile("s_waitcnt vmcnt(5)"  ::: "memory")
#define VM0()   asm volatile("s_waitcnt vmcnt(0)"  ::: "memory")
#define LGKM0() asm volatile("s_waitcnt lgkmcnt(0)" ::: "memory")
#define SB0()   __builtin_amdgcn_sched_barrier(0)
#define BAR()   __builtin_amdgcn_s_barrier()

__device__ __forceinline__ float fsigmoid(float x) { return 1.f / (1.f + __expf(-x)); }
__device__ __forceinline__ float ftanh_(float x) { return 1.f - 2.f / (__expf(2.f * x) + 1.f); }
__device__ __forceinline__ float bf2f(unsigned short u) {
  unsigned x = ((unsigned)u) << 16; float f; __builtin_memcpy(&f, &x, 4); return f;
}
__device__ __forceinline__ short f2bf_s(float x) {
  bf16 v = __float2bfloat16(x); short s; __builtin_memcpy(&s, &v, 2); return s;
}

// ---------------------------------------------------------------------------
// GEMM1: x = [h(t-d);h(t);h(t+d);spect] @ Wstack^T ; acts = tanh(x1)*sig(x2)
// R16 staging/sync verbatim; MFMA shape switched to 32x32x16_bf16:
// same LDS bytes, 8 MFMAs/chunk instead of 16 at higher rate, ~half VALU.
// Block 4 waves (2m x 2n) = 128 rows x (64 tanh + 64 sig); wave 64 x (32+32);
// acc = 2 classes x 2 row-tiles x f32x16 = 64 regs (3 waves/SIMD).
// A-frag (32x32x16): lane holds A[row=lane&31][k-octet=lane>>5]; B mirrors.
// C/D: col=lane&31, row=(r&3)+8*(r>>2)+4*(lane>>5)  [guide m74/m101].
// ---------------------------------------------------------------------------
__global__ __launch_bounds__(256, 3) void gemm1_kernel(
    const bf16* __restrict__ hpad, const bf16* __restrict__ spect,
    const bf16* __restrict__ wx,   // this layer: [44][4][512][8]
    const float* __restrict__ xb,  // [512] combined in_b + cond_b
    bf16* __restrict__ acts, int dil)
{
  // slot (shorts): A [4 kc][128 t][8]=4096, B1 [4][64 n][8]=2048, B2 2048
  __shared__ alignas(16) short lds[2 * 8192];    // 32 KB

  const int tid  = threadIdx.x;
  const int lane = tid & 63;
  const int wid  = tid >> 6;
  const int wm   = wid >> 1;          // 0..1
  const int wn   = wid & 1;           // 0..1

  const int bx  = blockIdx.x;                      // 512 m-tiles
  const int swz = ((bx & 7) << 6) | (bx >> 3);     // bijective on [0,512)
  const int m0 = swz * 128;
  const int c0 = blockIdx.y * 64;     // tanh channel tile: 0/64/128/192
  const int b  = m0 >> 12;            // tile fully inside one batch
  const int t0 = m0 & (SEQT - 1);

  f32x16 acc1[2], acc2[2];
#pragma unroll
  for (int i = 0; i < 2; ++i)
#pragma unroll
    for (int r = 0; r < 16; ++r) { acc1[i][r] = 0.f; acc2[i][r] = 0.f; }

  const int tA  = tid & 127;
  const int ccA = tid >> 7;           // 0..1 -> stages cc=ccA, ccA+2
  const int nB  = tid & 63;
  const int kcB = tid >> 6;           // 0..3

  const bf16* pAh = hpad  + (((size_t)b * 32 + ccA) * TPAD + PADT + t0 + tA) * 8;
  const bf16* pAs = spect + (((size_t)b * 80 + ccA) * 4096 + t0 + tA) * 8;
  const bf16* pB1 = wx + ((size_t)(kcB * 512) + c0 + nB) * 8;
  const bf16* pB2 = pB1 + 2048;       // +256 cols (sigmoid class)
  const ptrdiff_t dil8 = (ptrdiff_t)dil * 8;

  auto stage = [&](int kt) {
    short* base = lds + (kt & 1) * 8192;
    const bf16* a0;
    ptrdiff_t astep;
    if (kt < 24) {
      const int tap = kt >> 3;                       // 0,1,2
      a0 = pAh + (ptrdiff_t)((kt & 7) * 4) * (TPAD * 8) + (ptrdiff_t)(tap - 1) * dil8;
      astep = (ptrdiff_t)2 * TPAD * 8;
    } else {
      a0 = pAs + (ptrdiff_t)(kt - 24) * 131072;      // 4*4096*8
      astep = (ptrdiff_t)2 * 4096 * 8;
    }
    const bf16* w1 = pB1 + (ptrdiff_t)kt * 16384;    // 4*512*8
    const bf16* w2 = pB2 + (ptrdiff_t)kt * 16384;
    g2l16(a0,         base + (ccA * 128 + tA) * 8);
    g2l16(a0 + astep, base + ((ccA + 2) * 128 + tA) * 8);
    g2l16(w1,         base + 4096 + (kcB * 64 + nB) * 8);
    g2l16(w2,         base + 6144 + (kcB * 64 + nB) * 8);
  };

  const int c32 = lane & 31;          // 32x32 frag row/col
  const int h32 = lane >> 5;          // k-octet 0..1

  stage(0);                            // PROLOGUE
  for (int kt = 0; kt < 44; ++kt) {
    if (kt < 43) { stage(kt + 1); VM4(); }
    else         { VM0(); }
    BAR();                             // slot kt&1 fully staged (all waves)

    const short* cur = lds + (kt & 1) * 8192;
    // A frags: [i row-tile][s kstep]; kc chunk = s*2 + h32
    short8 af[2][2], bfa[2], bfb[2];
#pragma unroll
    for (int i = 0; i < 2; ++i)
#pragma unroll
      for (int s = 0; s < 2; ++s)
        af[i][s] = *(const short8*)(cur + ((s * 2 + h32) * 128 + wm * 64 + i * 32 + c32) * 8);
#pragma unroll
    for (int s = 0; s < 2; ++s) {
      bfa[s] = *(const short8*)(cur + 4096 + ((s * 2 + h32) * 64 + wn * 32 + c32) * 8);
      bfb[s] = *(const short8*)(cur + 6144 + ((s * 2 + h32) * 64 + wn * 32 + c32) * 8);
    }
    LGKM0();
    SB0();
    BAR();                             // all reads of slot kt&1 retired
    __builtin_amdgcn_s_setprio(1);
#pragma unroll
    for (int s = 0; s < 2; ++s)
#pragma unroll
      for (int i = 0; i < 2; ++i) {
        acc1[i] = __builtin_amdgcn_mfma_f32_32x32x16_bf16(af[i][s], bfa[s], acc1[i], 0, 0, 0);
        acc2[i] = __builtin_amdgcn_mfma_f32_32x32x16_bf16(af[i][s], bfb[s], acc2[i], 0, 0, 0);
      }
    __builtin_amdgcn_s_setprio(0);
  }

  // ---- epilogue: gate -> LDS bounce [8 cc'][128 t][8] -> coalesced stores
  short* obuf = lds;                   // 16 KB (slot 0; last chunk used slot 1)
  const int lc = wn * 32 + c32;        // local tanh channel 0..63
  const float bx1 = xb[c0 + lc];
  const float bx2 = xb[c0 + lc + 256];
#pragma unroll
  for (int i = 0; i < 2; ++i) {
#pragma unroll
    for (int r = 0; r < 16; ++r) {
      const int row = (r & 3) + 8 * (r >> 2) + 4 * h32;      // 0..31
      const int t = wm * 64 + i * 32 + row;                  // 0..127
      const float x1 = acc1[i][r] + bx1;
      const float x2 = acc2[i][r] + bx2;
      obuf[((lc >> 3) * 128 + t) * 8 + (lc & 7)] = f2bf_s(ftanh_(x1) * fsigmoid(x2));
    }
  }
  __syncthreads();
  const int tt = tid & 127;
  const int c2 = tid >> 7;            // 0..1
  short* ag = (short*)acts;
#pragma unroll
  for (int q = 0; q < 4; ++q) {
    const int ccp = c2 * 4 + q;       // 0..7
    const short8 v = *(const short8*)(obuf + (ccp * 128 + tt) * 8);
    *(short8*)(ag + ((size_t)(b * 32 + (c0 >> 3) + ccp) * 4096 + t0 + tt) * 8) = v;
  }
}

// ---------------------------------------------------------------------------
// GEMM2: rs = acts @ Wr^T (+rb); blockIdx.y==0 -> h += rs ; ==1 -> skip += rs
// R13 structure (64 rows x 256 cols, acc 64 AGPR) + R15 coalesced epilogues.
// ---------------------------------------------------------------------------
__global__ __launch_bounds__(256, 3) void gemm2_kernel(
    const bf16* __restrict__ acts, const bf16* __restrict__ wr,  // [8][4][512][8]
    const float* __restrict__ rb, bf16* __restrict__ hpad,
    bf16* __restrict__ skip, const int first)
{
  // slot (shorts): A [4 kc][64 t][8]=2048, B [4 kc][256 n][8]=8192
  __shared__ alignas(16) short lds[2 * 10240];   // 40 KB (obuf needs 32 KB)

  const int tid  = threadIdx.x;
  const int lane = tid & 63;
  const int wid  = tid >> 6;
  const int wm   = wid >> 1;          // 0..1
  const int wn   = wid & 1;           // 0..1

  const int bx  = blockIdx.x;
  const int swz = ((bx & 7) << 7) | (bx >> 3);     // bijective on [0,1024)
  const int m0 = swz * 64;
  const int n0 = blockIdx.y * 256;    // 0 (h-update) or 256 (skip)
  const int b  = m0 >> 12;
  const int t0 = m0 & (SEQT - 1);

  const f32x4 fzero = {0.f, 0.f, 0.f, 0.f};
  f32x4 acc[2][8];
#pragma unroll
  for (int i = 0; i < 2; ++i)
#pragma unroll
    for (int j = 0; j < 8; ++j) acc[i][j] = fzero;

  const int tA  = tid & 63;
  const int ccA = tid >> 6;           // 0..3

  const bf16* pA = acts + (((size_t)b * 32 + ccA) * 4096 + t0 + tA) * 8;
  const bf16* pB = wr + ((size_t)n0 + tid) * 8;    // col n0+tid, all 4 kc

  auto stage = [&](int kt) {
    short* base = lds + (kt & 1) * 10240;
    const bf16* a0 = pA + (ptrdiff_t)kt * 131072;  // 4*4096*8
    const bf16* w0 = pB + (ptrdiff_t)kt * 16384;   // 4*512*8
    g2l16(a0, base + (ccA * 64 + tA) * 8);
#pragma unroll
    for (int kcq = 0; kcq < 4; ++kcq)
      g2l16(w0 + kcq * 4096, base + 2048 + (kcq * 256 + tid) * 8);
  };

  const int rl = lane & 15;
  const int kc = lane >> 4;

  stage(0);                            // PROLOGUE
  for (int kt = 0; kt < 8; ++kt) {
    if (kt < 7) { stage(kt + 1); VM5(); }
    else        { VM0(); }
    BAR();

    const short* cur = lds + (kt & 1) * 10240;
    short8 af[2], bfr[8];
#pragma unroll
    for (int f = 0; f < 2; ++f)
      af[f] = *(const short8*)(cur + (kc * 64 + wm * 32 + f * 16 + rl) * 8);
#pragma unroll
    for (int j = 0; j < 8; ++j)
      bfr[j] = *(const short8*)(cur + 2048 + (kc * 256 + wn * 128 + j * 16 + rl) * 8);
    LGKM0();
    SB0();
    BAR();
    __builtin_amdgcn_s_setprio(1);
#pragma unroll
    for (int i = 0; i < 2; ++i)
#pragma unroll
      for (int j = 0; j < 8; ++j)
        acc[i][j] = __builtin_amdgcn_mfma_f32_16x16x32_bf16(af[i], bfr[j], acc[i][j], 0, 0, 0);
    __builtin_amdgcn_s_setprio(0);
  }

  // ---- epilogue: rs+bias -> LDS bounce -> coalesced RMW
  short* obuf = lds;
  const int rl2 = lane & 15;
  const int ro  = (lane >> 4) * 4;
  if (n0 == 0) {
    // h-update: obuf NC8 [32 cc][64 t][8] = 32 KB
#pragma unroll
    for (int i = 0; i < 2; ++i) {
#pragma unroll
      for (int j = 0; j < 8; ++j) {
        const int n = wn * 128 + j * 16 + rl2;       // 0..255
        const float bias = rb[n];
#pragma unroll
        for (int r = 0; r < 4; ++r) {
          const int t = wm * 32 + i * 16 + ro + r;
          obuf[((n >> 3) * 64 + t) * 8 + (n & 7)] = f2bf_s(acc[i][j][r] + bias);
        }
      }
    }
    __syncthreads();
    const int tt = tid & 63;
    const int c4 = tid >> 6;
    short* hg = (short*)hpad;
#pragma unroll
    for (int q = 0; q < 8; ++q) {
      const int cc = c4 * 8 + q;                     // 0..31
      const size_t gi = (((size_t)b * 32 + cc) * TPAD + PADT + t0 + tt) * 8;
      short8 hv = *(const short8*)(hg + gi);
      const short8 rv = *(const short8*)(obuf + (cc * 64 + tt) * 8);
      short8 ov;
#pragma unroll
      for (int w = 0; w < 8; ++w)
        ov[w] = f2bf_s(bf2f((unsigned short)hv[w]) + bf2f((unsigned short)rv[w]));
      *(short8*)(hg + gi) = ov;
    }
  } else {
    // skip: obuf row-major [64 t][256 n] = 32 KB
#pragma unroll
    for (int i = 0; i < 2; ++i) {
#pragma unroll
      for (int j = 0; j < 8; ++j) {
        const int n = wn * 128 + j * 16 + rl2;       // 0..255
        const float bias = rb[256 + n];
#pragma unroll
        for (int r = 0; r < 4; ++r) {
          const int t = wm * 32 + i * 16 + ro + r;
          obuf[t * 256 + n] = f2bf_s(acc[i][j][r] + bias);
        }
      }
    }
    __syncthreads();
    short* sg = (short*)skip;
#pragma unroll
    for (int q = 0; q < 8; ++q) {
      const int idx = q * 256 + tid;                 // 0..2047 chunks
      const int t  = idx >> 5;
      const int nc = idx & 31;
      const size_t gi = ((size_t)(b * SEQT + t0 + t)) * NCH + nc * 8;
      const short8 rv = *(const short8*)(obuf + t * 256 + nc * 8);
      if (first) {
        *(short8*)(sg + gi) = rv;
      } else {
        short8 sv = *(const short8*)(sg + gi);
        short8 ov;
#pragma unroll
        for (int w = 0; w < 8; ++w)
          ov[w] = f2bf_s(bf2f((unsigned short)sv[w]) + bf2f((unsigned short)rv[w]));
        *(short8*)(sg + gi) = ov;
      }
    }
  }
}

// ---------------------------------------------------------------------------
// aux kernels
// ---------------------------------------------------------------------------
__global__ void start_kernel(const float* __restrict__ audio, const float* __restrict__ sw,
                             const float* __restrict__ sb, bf16* __restrict__ hpad)
{
  const int idx = blockIdx.x * 256 + threadIdx.x;   // < 16777216
  const int w  = idx & 7;
  const int t  = (idx >> 3) & 4095;
  const int cc = (idx >> 15) & 31;
  const int b  = idx >> 20;
  const int c  = cc * 8 + w;
  const float* a = audio + ((size_t)(b * SEQT + t)) * 4;
  float v = sb[c] + a[0] * sw[c] + a[1] * sw[256 + c] + a[2] * sw[512 + c] + a[3] * sw[768 + c];
  hpad[(((size_t)b * 32 + cc) * TPAD + PADT + t) * 8 + w] = __float2bfloat16(v);
}

__global__ void cvt_spect_kernel(const float* __restrict__ s, bf16* __restrict__ d)
{
  const size_t idx = (size_t)blockIdx.x * 256 + threadIdx.x;  // < 41943040
  const int w  = (int)(idx & 7);
  const int t  = (int)((idx >> 3) & 4095);
  const unsigned q = (unsigned)(idx >> 15);     // b*80 + cc
  const int b  = q / 80;
  const int cc = q % 80;
  const int c  = cc * 8 + w;
  d[idx] = __float2bfloat16(s[((size_t)(b * SEQT + t)) * NMEL + c]);
}

__global__ void prep_wx_kernel(const float* __restrict__ in_w, const float* __restrict__ cond_w,
                               bf16* __restrict__ wx)
{
  const size_t idx = (size_t)blockIdx.x * 256 + threadIdx.x;
  if (idx >= (size_t)LAYERS * 44 * 4 * 512 * 8) return;
  const int w   = (int)(idx & 7);
  const int n   = (int)((idx >> 3) & 511);
  const int kc  = (int)((idx >> 12) & 3);
  const unsigned ktp = (unsigned)(idx >> 14);   // i*44 + kt
  const int i  = ktp / 44;
  const int kt = ktp % 44;
  const int k  = kt * 32 + kc * 8 + w;
  float v;
  if (k < 768) {
    const int tap = k >> 8;
    const int c   = k & 255;
    v = in_w[(size_t)(((i * 3 + tap) << 8) + c) * 512 + n];
  } else {
    v = cond_w[((size_t)i * NMEL + (k - 768)) * 512 + n];
  }
  wx[idx] = __float2bfloat16(v);
}

__global__ void prep_wr_kernel(const float* __restrict__ rs_w, const float* __restrict__ rs_w_last,
                               bf16* __restrict__ wr)
{
  const int idx = blockIdx.x * 256 + threadIdx.x;   // < 1048576
  const int w  = idx & 7;
  const int n  = (idx >> 3) & 511;
  const int kc = (idx >> 12) & 3;
  const int kt = (idx >> 14) & 7;
  const int i  = idx >> 17;
  const int k  = kt * 32 + kc * 8 + w;              // [0,256)
  float v;
  if (i < LAYERS - 1) v = rs_w[(size_t)((i << 8) + k) * 512 + n];
  else                v = (n >= 256) ? rs_w_last[(k << 8) + (n - 256)] : 0.f;
  wr[idx] = __float2bfloat16(v);
}

__global__ void prep_bias_kernel(const float* __restrict__ in_b, const float* __restrict__ cond_b,
                                 const float* __restrict__ rs_b, const float* __restrict__ rs_b_last,
                                 float* __restrict__ xb, float* __restrict__ rb)
{
  const int idx = blockIdx.x * 256 + threadIdx.x;   // < 4096
  if (idx >= LAYERS * 512) return;
  const int i = idx >> 9;
  const int n = idx & 511;
  xb[idx] = in_b[idx] + cond_b[idx];
  rb[idx] = (i < LAYERS - 1) ? rs_b[idx] : ((n >= 256) ? rs_b_last[n - 256] : 0.f);
}

__global__ void end_kernel(const bf16* __restrict__ skip, const float* __restrict__ ew,
                           const float* __restrict__ eb, float* __restrict__ out)
{
  const int idx = blockIdx.x * 256 + threadIdx.x;   // < 524288
  const int m = idx >> 3;
  const int j = idx & 7;
  const bf16* srow = skip + (size_t)m * NCH;
  float s = eb[j];
#pragma unroll 4
  for (int c8 = 0; c8 < NCH / 8; ++c8) {
    short8 v = *(const short8*)(srow + c8 * 8);
#pragma unroll
    for (int w = 0; w < 8; ++w)
      s += bf2f((unsigned short)v[w]) * ew[(c8 * 8 + w) * 8 + j];
  }
  out[idx] = s;
}

// ---------------------------------------------------------------------------
extern "C" void kernel_launch(void* const* d_in, const int* in_sizes, int n_in,
                              void* d_out, int out_size, void* d_ws, size_t ws_size,
                              hipStream_t stream)
{
  const float* audio     = (const float*)d_in[0];
  const float* spect     = (const float*)d_in[1];
  const float* start_w   = (const float*)d_in[2];
  const float* start_b   = (const float*)d_in[3];
  const float* in_w      = (const float*)d_in[4];
  const float* in_b      = (const float*)d_in[5];
  const float* cond_w    = (const float*)d_in[6];
  const float* cond_b    = (const float*)d_in[7];
  const float* rs_w      = (const float*)d_in[8];
  const float* rs_b      = (const float*)d_in[9];
  const float* rs_w_last = (const float*)d_in[10];
  const float* rs_b_last = (const float*)d_in[11];
  const float* end_w     = (const float*)d_in[12];
  const float* end_b     = (const float*)d_in[13];
  float* out = (float*)d_out;

  char* p = (char*)d_ws;
  bf16* spect_bf = (bf16*)p;  p += (size_t)BTROWS * NMEL * 2;          // 83.9 MB
  bf16* hpad     = (bf16*)p;  p += (size_t)NBATCH * 32 * TPAD * 8 * 2; // 35.7 MB
  bf16* actsb    = (bf16*)p;  p += (size_t)BTROWS * NCH * 2;           // 33.6 MB
  bf16* skip     = (bf16*)p;  p += (size_t)BTROWS * NCH * 2;           // 33.6 MB
  bf16* wx       = (bf16*)p;  p += (size_t)LAYERS * 512 * KX * 2;      // 11.5 MB
  bf16* wr       = (bf16*)p;  p += (size_t)LAYERS * 512 * 256 * 2;     //  2.1 MB
  float* xb      = (float*)p; p += (size_t)LAYERS * 512 * 4;
  float* rb      = (float*)p; p += (size_t)LAYERS * 512 * 4;
  if ((size_t)(p - (char*)d_ws) > ws_size) return;  // insufficient workspace

  hipMemsetAsync(hpad, 0, (size_t)NBATCH * 32 * TPAD * 8 * 2, stream);
  prep_wx_kernel<<<(LAYERS * 512 * KX + 255) / 256, 256, 0, stream>>>(in_w, cond_w, wx);
  prep_wr_kernel<<<(LAYERS * 512 * 256) / 256, 256, 0, stream>>>(rs_w, rs_w_last, wr);
  prep_bias_kernel<<<16, 256, 0, stream>>>(in_b, cond_b, rs_b, rs_b_last, xb, rb);
  cvt_spect_kernel<<<(BTROWS * NMEL) / 256, 256, 0, stream>>>(spect, spect_bf);
  start_kernel<<<(BTROWS * NCH) / 256, 256, 0, stream>>>(audio, start_w, start_b, hpad);

  for (int i = 0; i < LAYERS; ++i) {
    gemm1_kernel<<<dim3(512, 4), 256, 0, stream>>>(hpad, spect_bf, wx + (size_t)i * 44 * 4 * 512 * 8,
                                                   xb + i * 512, actsb, 1 << i);
    gemm2_kernel<<<dim3(1024, 2), 256, 0, stream>>>(actsb, wr + (size_t)i * 8 * 4 * 512 * 8,
                                                    rb + i * 512, hpad, skip, i == 0 ? 1 : 0);
  }
  end_kernel<<<(BTROWS * 8) / 256, 256, 0, stream>>>(skip, end_w, end_b, out);
}

// Round 19
// 1196.930 us; speedup vs baseline: 1.1073x; 1.0938x over previous
//
#include <hip/hip_runtime.h>
#include <hip/hip_bf16.h>
#include <stdint.h>
#include <stddef.h>

#define LAYERS 8
#define NCH 256
#define NMEL 640
#define NBATCH 16
#define SEQT 4096
#define BTROWS (NBATCH * SEQT)   // 65536
#define PADT 128
#define TPAD (SEQT + 2 * PADT)   // 4352
#define KX 1408                  // 3*256 + 640

// NC8 layouts (all bf16, inner dim = 8 channels/k):
//  hpad : [b][32 cc][TPAD t][8]
//  spect: [b][80 cc][4096 t][8]
//  acts : [b][32 cc][4096 t][8]
//  wx   : [layer][44 kt][4 kc][512 n][8]
//  wr   : [layer][ 8 kt][4 kc][512 n][8]
//  skip : [m][256]  (row-major, feeds end_kernel)

typedef __hip_bfloat16 bf16;
typedef __attribute__((ext_vector_type(8))) short short8;
typedef __attribute__((ext_vector_type(4))) float f32x4;

__device__ __forceinline__ void g2l16(const void* g, void* l) {
  __builtin_amdgcn_global_load_lds(
      (const __attribute__((address_space(1))) unsigned int*)g,
      (__attribute__((address_space(3))) unsigned int*)l, 16, 0, 0);
}

#define VM4()   asm volatile("s_waitcnt vmcnt(4)"  ::: "memory")
#define VM5()   asm volatile("s_waitcnt vmcnt(5)"  ::: "memory")
#define VM0()   asm volatile("s_waitcnt vmcnt(0)"  ::: "memory")
#define LGKM0() asm volatile("s_waitcnt lgkmcnt(0)" ::: "memory")
#define SB0()   __builtin_amdgcn_sched_barrier(0)
#define BAR()   __builtin_amdgcn_s_barrier()

__device__ __forceinline__ float fsigmoid(float x) { return 1.f / (1.f + __expf(-x)); }
__device__ __forceinline__ float ftanh_(float x) { return 1.f - 2.f / (__expf(2.f * x) + 1.f); }
__device__ __forceinline__ float bf2f(unsigned short u) {
  unsigned x = ((unsigned)u) << 16; float f; __builtin_memcpy(&f, &x, 4); return f;
}
__device__ __forceinline__ short f2bf_s(float x) {
  bf16 v = __float2bfloat16(x); short s; __builtin_memcpy(&s, &v, 2); return s;
}

// ---------------------------------------------------------------------------
// GEMM1: x = [h(t-d);h(t);h(t+d);spect] @ Wstack^T ; acts = tanh(x1)*sig(x2)
// R16 structure (16x16x32, 4 waves 2m x 2n, 128 rows x (64t+64s), acc 64,
// ring-2 16KB slots, counted-vmcnt sync, coalesced LDS-bounce epilogue).
// NEW: 1-D grid, xcd-major sibling-adjacent mapping -- the 4 channel-slices
// (y) of one m-tile are dispatch-adjacent on ONE XCD, so the 360KB A-slice
// is fetched once into that XCD's L2 instead of 4x from HBM.
//   id = blockIdx.x ; xcd = id&7 ; seq = id>>3 ; tile = seq>>2 ; y = seq&3
//   m0 = (xcd*64 + tile)*128 ; c0 = y*64
// ---------------------------------------------------------------------------
__global__ __launch_bounds__(256, 3) void gemm1_kernel(
    const bf16* __restrict__ hpad, const bf16* __restrict__ spect,
    const bf16* __restrict__ wx,   // this layer: [44][4][512][8]
    const float* __restrict__ xb,  // [512] combined in_b + cond_b
    bf16* __restrict__ acts, int dil)
{
  // slot (shorts): A [4 kc][128 t][8]=4096, B1 [4][64 n][8]=2048, B2 2048
  __shared__ alignas(16) short lds[2 * 8192];    // 32 KB

  const int tid  = threadIdx.x;
  const int lane = tid & 63;
  const int wid  = tid >> 6;
  const int wm   = wid >> 1;          // 0..1
  const int wn   = wid & 1;           // 0..1

  const int id   = blockIdx.x;        // 2048 blocks
  const int xcd  = id & 7;
  const int seq  = id >> 3;
  const int tile = seq >> 2;          // 0..63
  const int y    = seq & 3;
  const int m0 = (xcd * 64 + tile) * 128;
  const int c0 = y * 64;              // tanh channel tile: 0/64/128/192
  const int b  = m0 >> 12;            // tile fully inside one batch
  const int t0 = m0 & (SEQT - 1);

  const f32x4 fzero = {0.f, 0.f, 0.f, 0.f};
  f32x4 acc1[4][2], acc2[4][2];
#pragma unroll
  for (int i = 0; i < 4; ++i)
#pragma unroll
    for (int j = 0; j < 2; ++j) { acc1[i][j] = fzero; acc2[i][j] = fzero; }

  const int tA  = tid & 127;
  const int ccA = tid >> 7;           // 0..1 -> stages cc=ccA, ccA+2
  const int nB  = tid & 63;
  const int kcB = tid >> 6;           // 0..3

  const bf16* pAh = hpad  + (((size_t)b * 32 + ccA) * TPAD + PADT + t0 + tA) * 8;
  const bf16* pAs = spect + (((size_t)b * 80 + ccA) * 4096 + t0 + tA) * 8;
  const bf16* pB1 = wx + ((size_t)(kcB * 512) + c0 + nB) * 8;
  const bf16* pB2 = pB1 + 2048;       // +256 cols (sigmoid class)
  const ptrdiff_t dil8 = (ptrdiff_t)dil * 8;

  auto stage = [&](int kt) {
    short* base = lds + (kt & 1) * 8192;
    const bf16* a0;
    ptrdiff_t astep;
    if (kt < 24) {
      const int tap = kt >> 3;                       // 0,1,2
      a0 = pAh + (ptrdiff_t)((kt & 7) * 4) * (TPAD * 8) + (ptrdiff_t)(tap - 1) * dil8;
      astep = (ptrdiff_t)2 * TPAD * 8;
    } else {
      a0 = pAs + (ptrdiff_t)(kt - 24) * 131072;      // 4*4096*8
      astep = (ptrdiff_t)2 * 4096 * 8;
    }
    const bf16* w1 = pB1 + (ptrdiff_t)kt * 16384;    // 4*512*8
    const bf16* w2 = pB2 + (ptrdiff_t)kt * 16384;
    g2l16(a0,         base + (ccA * 128 + tA) * 8);
    g2l16(a0 + astep, base + ((ccA + 2) * 128 + tA) * 8);
    g2l16(w1,         base + 4096 + (kcB * 64 + nB) * 8);
    g2l16(w2,         base + 6144 + (kcB * 64 + nB) * 8);
  };

  const int rl = lane & 15;
  const int kc = lane >> 4;           // 0..3

  stage(0);                            // PROLOGUE
  for (int kt = 0; kt < 44; ++kt) {
    if (kt < 43) { stage(kt + 1); VM4(); }
    else         { VM0(); }
    BAR();                             // slot kt&1 fully staged (all waves)

    const short* cur = lds + (kt & 1) * 8192;
    short8 af[4], bfa[2], bfb[2];
#pragma unroll
    for (int f = 0; f < 4; ++f)
      af[f]  = *(const short8*)(cur + (kc * 128 + wm * 64 + f * 16 + rl) * 8);
#pragma unroll
    for (int j = 0; j < 2; ++j) {
      bfa[j] = *(const short8*)(cur + 4096 + (kc * 64 + wn * 32 + j * 16 + rl) * 8);
      bfb[j] = *(const short8*)(cur + 6144 + (kc * 64 + wn * 32 + j * 16 + rl) * 8);
    }
    LGKM0();
    SB0();
    BAR();                             // all reads of slot kt&1 retired
    __builtin_amdgcn_s_setprio(1);
#pragma unroll
    for (int i = 0; i < 4; ++i)
#pragma unroll
      for (int j = 0; j < 2; ++j) {
        acc1[i][j] = __builtin_amdgcn_mfma_f32_16x16x32_bf16(af[i], bfa[j], acc1[i][j], 0, 0, 0);
        acc2[i][j] = __builtin_amdgcn_mfma_f32_16x16x32_bf16(af[i], bfb[j], acc2[i][j], 0, 0, 0);
      }
    __builtin_amdgcn_s_setprio(0);
  }

  // ---- epilogue: gate -> LDS bounce [8 cc'][128 t][8] -> coalesced stores
  short* obuf = lds;                   // 16 KB (slot 0; last chunk used slot 1)
  const int rl2 = lane & 15;
  const int ro  = (lane >> 4) * 4;
#pragma unroll
  for (int i = 0; i < 4; ++i) {
#pragma unroll
    for (int j = 0; j < 2; ++j) {
      const int lc = wn * 32 + j * 16 + rl2;         // local tanh ch 0..63
      const float bx1 = xb[c0 + lc];
      const float bx2 = xb[c0 + lc + 256];
#pragma unroll
      for (int r = 0; r < 4; ++r) {
        const int t = wm * 64 + i * 16 + ro + r;     // 0..127
        const float x1 = acc1[i][j][r] + bx1;
        const float x2 = acc2[i][j][r] + bx2;
        obuf[((lc >> 3) * 128 + t) * 8 + (lc & 7)] = f2bf_s(ftanh_(x1) * fsigmoid(x2));
      }
    }
  }
  __syncthreads();
  const int tt = tid & 127;
  const int c2 = tid >> 7;            // 0..1
  short* ag = (short*)acts;
#pragma unroll
  for (int q = 0; q < 4; ++q) {
    const int ccp = c2 * 4 + q;       // 0..7
    const short8 v = *(const short8*)(obuf + (ccp * 128 + tt) * 8);
    *(short8*)(ag + ((size_t)(b * 32 + (c0 >> 3) + ccp) * 4096 + t0 + tt) * 8) = v;
  }
}

// ---------------------------------------------------------------------------
// GEMM2: rs = acts @ Wr^T (+rb); blockIdx.y==0 -> h += rs ; ==1 -> skip += rs
// R13 structure (64 rows x 256 cols, acc 64 AGPR) + R15 coalesced epilogues.
// ---------------------------------------------------------------------------
__global__ __launch_bounds__(256, 3) void gemm2_kernel(
    const bf16* __restrict__ acts, const bf16* __restrict__ wr,  // [8][4][512][8]
    const float* __restrict__ rb, bf16* __restrict__ hpad,
    bf16* __restrict__ skip, const int first)
{
  // slot (shorts): A [4 kc][64 t][8]=2048, B [4 kc][256 n][8]=8192
  __shared__ alignas(16) short lds[2 * 10240];   // 40 KB (obuf needs 32 KB)

  const int tid  = threadIdx.x;
  const int lane = tid & 63;
  const int wid  = tid >> 6;
  const int wm   = wid >> 1;          // 0..1
  const int wn   = wid & 1;           // 0..1

  const int bx  = blockIdx.x;
  const int swz = ((bx & 7) << 7) | (bx >> 3);     // bijective on [0,1024)
  const int m0 = swz * 64;
  const int n0 = blockIdx.y * 256;    // 0 (h-update) or 256 (skip)
  const int b  = m0 >> 12;
  const int t0 = m0 & (SEQT - 1);

  const f32x4 fzero = {0.f, 0.f, 0.f, 0.f};
  f32x4 acc[2][8];
#pragma unroll
  for (int i = 0; i < 2; ++i)
#pragma unroll
    for (int j = 0; j < 8; ++j) acc[i][j] = fzero;

  const int tA  = tid & 63;
  const int ccA = tid >> 6;           // 0..3

  const bf16* pA = acts + (((size_t)b * 32 + ccA) * 4096 + t0 + tA) * 8;
  const bf16* pB = wr + ((size_t)n0 + tid) * 8;    // col n0+tid, all 4 kc

  auto stage = [&](int kt) {
    short* base = lds + (kt & 1) * 10240;
    const bf16* a0 = pA + (ptrdiff_t)kt * 131072;  // 4*4096*8
    const bf16* w0 = pB + (ptrdiff_t)kt * 16384;   // 4*512*8
    g2l16(a0, base + (ccA * 64 + tA) * 8);
#pragma unroll
    for (int kcq = 0; kcq < 4; ++kcq)
      g2l16(w0 + kcq * 4096, base + 2048 + (kcq * 256 + tid) * 8);
  };

  const int rl = lane & 15;
  const int kc = lane >> 4;

  stage(0);                            // PROLOGUE
  for (int kt = 0; kt < 8; ++kt) {
    if (kt < 7) { stage(kt + 1); VM5(); }
    else        { VM0(); }
    BAR();

    const short* cur = lds + (kt & 1) * 10240;
    short8 af[2], bfr[8];
#pragma unroll
    for (int f = 0; f < 2; ++f)
      af[f] = *(const short8*)(cur + (kc * 64 + wm * 32 + f * 16 + rl) * 8);
#pragma unroll
    for (int j = 0; j < 8; ++j)
      bfr[j] = *(const short8*)(cur + 2048 + (kc * 256 + wn * 128 + j * 16 + rl) * 8);
    LGKM0();
    SB0();
    BAR();
    __builtin_amdgcn_s_setprio(1);
#pragma unroll
    for (int i = 0; i < 2; ++i)
#pragma unroll
      for (int j = 0; j < 8; ++j)
        acc[i][j] = __builtin_amdgcn_mfma_f32_16x16x32_bf16(af[i], bfr[j], acc[i][j], 0, 0, 0);
    __builtin_amdgcn_s_setprio(0);
  }

  // ---- epilogue: rs+bias -> LDS bounce -> coalesced RMW
  short* obuf = lds;
  const int rl2 = lane & 15;
  const int ro  = (lane >> 4) * 4;
  if (n0 == 0) {
    // h-update: obuf NC8 [32 cc][64 t][8] = 32 KB
#pragma unroll
    for (int i = 0; i < 2; ++i) {
#pragma unroll
      for (int j = 0; j < 8; ++j) {
        const int n = wn * 128 + j * 16 + rl2;       // 0..255
        const float bias = rb[n];
#pragma unroll
        for (int r = 0; r < 4; ++r) {
          const int t = wm * 32 + i * 16 + ro + r;
          obuf[((n >> 3) * 64 + t) * 8 + (n & 7)] = f2bf_s(acc[i][j][r] + bias);
        }
      }
    }
    __syncthreads();
    const int tt = tid & 63;
    const int c4 = tid >> 6;
    short* hg = (short*)hpad;
#pragma unroll
    for (int q = 0; q < 8; ++q) {
      const int cc = c4 * 8 + q;                     // 0..31
      const size_t gi = (((size_t)b * 32 + cc) * TPAD + PADT + t0 + tt) * 8;
      short8 hv = *(const short8*)(hg + gi);
      const short8 rv = *(const short8*)(obuf + (cc * 64 + tt) * 8);
      short8 ov;
#pragma unroll
      for (int w = 0; w < 8; ++w)
        ov[w] = f2bf_s(bf2f((unsigned short)hv[w]) + bf2f((unsigned short)rv[w]));
      *(short8*)(hg + gi) = ov;
    }
  } else {
    // skip: obuf row-major [64 t][256 n] = 32 KB
#pragma unroll
    for (int i = 0; i < 2; ++i) {
#pragma unroll
      for (int j = 0; j < 8; ++j) {
        const int n = wn * 128 + j * 16 + rl2;       // 0..255
        const float bias = rb[256 + n];
#pragma unroll
        for (int r = 0; r < 4; ++r) {
          const int t = wm * 32 + i * 16 + ro + r;
          obuf[t * 256 + n] = f2bf_s(acc[i][j][r] + bias);
        }
      }
    }
    __syncthreads();
    short* sg = (short*)skip;
#pragma unroll
    for (int q = 0; q < 8; ++q) {
      const int idx = q * 256 + tid;                 // 0..2047 chunks
      const int t  = idx >> 5;
      const int nc = idx & 31;
      const size_t gi = ((size_t)(b * SEQT + t0 + t)) * NCH + nc * 8;
      const short8 rv = *(const short8*)(obuf + t * 256 + nc * 8);
      if (first) {
        *(short8*)(sg + gi) = rv;
      } else {
        short8 sv = *(const short8*)(sg + gi);
        short8 ov;
#pragma unroll
        for (int w = 0; w < 8; ++w)
          ov[w] = f2bf_s(bf2f((unsigned short)sv[w]) + bf2f((unsigned short)rv[w]));
        *(short8*)(sg + gi) = ov;
      }
    }
  }
}

// ---------------------------------------------------------------------------
// aux kernels
// ---------------------------------------------------------------------------
__global__ void start_kernel(const float* __restrict__ audio, const float* __restrict__ sw,
                             const float* __restrict__ sb, bf16* __restrict__ hpad)
{
  const int idx = blockIdx.x * 256 + threadIdx.x;   // < 16777216
  const int w  = idx & 7;
  const int t  = (idx >> 3) & 4095;
  const int cc = (idx >> 15) & 31;
  const int b  = idx >> 20;
  const int c  = cc * 8 + w;
  const float* a = audio + ((size_t)(b * SEQT + t)) * 4;
  float v = sb[c] + a[0] * sw[c] + a[1] * sw[256 + c] + a[2] * sw[512 + c] + a[3] * sw[768 + c];
  hpad[(((size_t)b * 32 + cc) * TPAD + PADT + t) * 8 + w] = __float2bfloat16(v);
}

__global__ void cvt_spect_kernel(const float* __restrict__ s, bf16* __restrict__ d)
{
  const size_t idx = (size_t)blockIdx.x * 256 + threadIdx.x;  // < 41943040
  const int w  = (int)(idx & 7);
  const int t  = (int)((idx >> 3) & 4095);
  const unsigned q = (unsigned)(idx >> 15);     // b*80 + cc
  const int b  = q / 80;
  const int cc = q % 80;
  const int c  = cc * 8 + w;
  d[idx] = __float2bfloat16(s[((size_t)(b * SEQT + t)) * NMEL + c]);
}

__global__ void prep_wx_kernel(const float* __restrict__ in_w, const float* __restrict__ cond_w,
                               bf16* __restrict__ wx)
{
  const size_t idx = (size_t)blockIdx.x * 256 + threadIdx.x;
  if (idx >= (size_t)LAYERS * 44 * 4 * 512 * 8) return;
  const int w   = (int)(idx & 7);
  const int n   = (int)((idx >> 3) & 511);
  const int kc  = (int)((idx >> 12) & 3);
  const unsigned ktp = (unsigned)(idx >> 14);   // i*44 + kt
  const int i  = ktp / 44;
  const int kt = ktp % 44;
  const int k  = kt * 32 + kc * 8 + w;
  float v;
  if (k < 768) {
    const int tap = k >> 8;
    const int c   = k & 255;
    v = in_w[(size_t)(((i * 3 + tap) << 8) + c) * 512 + n];
  } else {
    v = cond_w[((size_t)i * NMEL + (k - 768)) * 512 + n];
  }
  wx[idx] = __float2bfloat16(v);
}

__global__ void prep_wr_kernel(const float* __restrict__ rs_w, const float* __restrict__ rs_w_last,
                               bf16* __restrict__ wr)
{
  const int idx = blockIdx.x * 256 + threadIdx.x;   // < 1048576
  const int w  = idx & 7;
  const int n  = (idx >> 3) & 511;
  const int kc = (idx >> 12) & 3;
  const int kt = (idx >> 14) & 7;
  const int i  = idx >> 17;
  const int k  = kt * 32 + kc * 8 + w;              // [0,256)
  float v;
  if (i < LAYERS - 1) v = rs_w[(size_t)((i << 8) + k) * 512 + n];
  else                v = (n >= 256) ? rs_w_last[(k << 8) + (n - 256)] : 0.f;
  wr[idx] = __float2bfloat16(v);
}

__global__ void prep_bias_kernel(const float* __restrict__ in_b, const float* __restrict__ cond_b,
                                 const float* __restrict__ rs_b, const float* __restrict__ rs_b_last,
                                 float* __restrict__ xb, float* __restrict__ rb)
{
  const int idx = blockIdx.x * 256 + threadIdx.x;   // < 4096
  if (idx >= LAYERS * 512) return;
  const int i = idx >> 9;
  const int n = idx & 511;
  xb[idx] = in_b[idx] + cond_b[idx];
  rb[idx] = (i < LAYERS - 1) ? rs_b[idx] : ((n >= 256) ? rs_b_last[n - 256] : 0.f);
}

__global__ void end_kernel(const bf16* __restrict__ skip, const float* __restrict__ ew,
                           const float* __restrict__ eb, float* __restrict__ out)
{
  const int idx = blockIdx.x * 256 + threadIdx.x;   // < 524288
  const int m = idx >> 3;
  const int j = idx & 7;
  const bf16* srow = skip + (size_t)m * NCH;
  float s = eb[j];
#pragma unroll 4
  for (int c8 = 0; c8 < NCH / 8; ++c8) {
    short8 v = *(const short8*)(srow + c8 * 8);
#pragma unroll
    for (int w = 0; w < 8; ++w)
      s += bf2f((unsigned short)v[w]) * ew[(c8 * 8 + w) * 8 + j];
  }
  out[idx] = s;
}

// ---------------------------------------------------------------------------
extern "C" void kernel_launch(void* const* d_in, const int* in_sizes, int n_in,
                              void* d_out, int out_size, void* d_ws, size_t ws_size,
                              hipStream_t stream)
{
  const float* audio     = (const float*)d_in[0];
  const float* spect     = (const float*)d_in[1];
  const float* start_w   = (const float*)d_in[2];
  const float* start_b   = (const float*)d_in[3];
  const float* in_w      = (const float*)d_in[4];
  const float* in_b      = (const float*)d_in[5];
  const float* cond_w    = (const float*)d_in[6];
  const float* cond_b    = (const float*)d_in[7];
  const float* rs_w      = (const float*)d_in[8];
  const float* rs_b      = (const float*)d_in[9];
  const float* rs_w_last = (const float*)d_in[10];
  const float* rs_b_last = (const float*)d_in[11];
  const float* end_w     = (const float*)d_in[12];
  const float* end_b     = (const float*)d_in[13];
  float* out = (float*)d_out;

  char* p = (char*)d_ws;
  bf16* spect_bf = (bf16*)p;  p += (size_t)BTROWS * NMEL * 2;          // 83.9 MB
  bf16* hpad     = (bf16*)p;  p += (size_t)NBATCH * 32 * TPAD * 8 * 2; // 35.7 MB
  bf16* actsb    = (bf16*)p;  p += (size_t)BTROWS * NCH * 2;           // 33.6 MB
  bf16* skip     = (bf16*)p;  p += (size_t)BTROWS * NCH * 2;           // 33.6 MB
  bf16* wx       = (bf16*)p;  p += (size_t)LAYERS * 512 * KX * 2;      // 11.5 MB
  bf16* wr       = (bf16*)p;  p += (size_t)LAYERS * 512 * 256 * 2;     //  2.1 MB
  float* xb      = (float*)p; p += (size_t)LAYERS * 512 * 4;
  float* rb      = (float*)p; p += (size_t)LAYERS * 512 * 4;
  if ((size_t)(p - (char*)d_ws) > ws_size) return;  // insufficient workspace

  hipMemsetAsync(hpad, 0, (size_t)NBATCH * 32 * TPAD * 8 * 2, stream);
  prep_wx_kernel<<<(LAYERS * 512 * KX + 255) / 256, 256, 0, stream>>>(in_w, cond_w, wx);
  prep_wr_kernel<<<(LAYERS * 512 * 256) / 256, 256, 0, stream>>>(rs_w, rs_w_last, wr);
  prep_bias_kernel<<<16, 256, 0, stream>>>(in_b, cond_b, rs_b, rs_b_last, xb, rb);
  cvt_spect_kernel<<<(BTROWS * NMEL) / 256, 256, 0, stream>>>(spect, spect_bf);
  start_kernel<<<(BTROWS * NCH) / 256, 256, 0, stream>>>(audio, start_w, start_b, hpad);

  for (int i = 0; i < LAYERS; ++i) {
    gemm1_kernel<<<2048, 256, 0, stream>>>(hpad, spect_bf, wx + (size_t)i * 44 * 4 * 512 * 8,
                                           xb + i * 512, actsb, 1 << i);
    gemm2_kernel<<<dim3(1024, 2), 256, 0, stream>>>(actsb, wr + (size_t)i * 8 * 4 * 512 * 8,
                                                    rb + i * 512, hpad, skip, i == 0 ? 1 : 0);
  }
  end_kernel<<<(BTROWS * 8) / 256, 256, 0, stream>>>(skip, end_w, end_b, out);
}

// Round 20
// 1176.671 us; speedup vs baseline: 1.1264x; 1.0172x over previous
//
#include <hip/hip_runtime.h>
#include <hip/hip_bf16.h>
#include <stdint.h>
#include <stddef.h>

#define LAYERS 8
#define NCH 256
#define NMEL 640
#define NBATCH 16
#define SEQT 4096
#define BTROWS (NBATCH * SEQT)   // 65536
#define PADT 128
#define TPAD (SEQT + 2 * PADT)   // 4352
#define KX 1408                  // 3*256 + 640

// NC8 layouts (all bf16, inner dim = 8 channels/k):
//  hpad : [b][32 cc][TPAD t][8]
//  spect: [b][80 cc][4096 t][8]
//  acts : [b][32 cc][4096 t][8]
//  wx   : [layer][44 kt][4 kc][512 n][8]
//  wr   : [layer][ 8 kt][4 kc][512 n][8]
//  skip : [m][256]  (row-major, feeds end_kernel)

typedef __hip_bfloat16 bf16;
typedef __attribute__((ext_vector_type(8))) short short8;
typedef __attribute__((ext_vector_type(4))) float f32x4;

__device__ __forceinline__ void g2l16(const void* g, void* l) {
  __builtin_amdgcn_global_load_lds(
      (const __attribute__((address_space(1))) unsigned int*)g,
      (__attribute__((address_space(3))) unsigned int*)l, 16, 0, 0);
}

#define VM4()   asm volatile("s_waitcnt vmcnt(4)"  ::: "memory")
#define VM5()   asm volatile("s_waitcnt vmcnt(5)"  ::: "memory")
#define VM0()   asm volatile("s_waitcnt vmcnt(0)"  ::: "memory")
#define LGKM0() asm volatile("s_waitcnt lgkmcnt(0)" ::: "memory")
#define SB0()   __builtin_amdgcn_sched_barrier(0)
#define BAR()   __builtin_amdgcn_s_barrier()

__device__ __forceinline__ float fsigmoid(float x) { return 1.f / (1.f + __expf(-x)); }
__device__ __forceinline__ float ftanh_(float x) { return 1.f - 2.f / (__expf(2.f * x) + 1.f); }
__device__ __forceinline__ float bf2f(unsigned short u) {
  unsigned x = ((unsigned)u) << 16; float f; __builtin_memcpy(&f, &x, 4); return f;
}
__device__ __forceinline__ short f2bf_s(float x) {
  bf16 v = __float2bfloat16(x); short s; __builtin_memcpy(&s, &v, 2); return s;
}

// ---------------------------------------------------------------------------
// GEMM1: x = [h(t-d);h(t);h(t+d);spect] @ Wstack^T ; acts = tanh(x1)*sig(x2)
// R19 structure + __launch_bounds__(256,4): VGPR 60 + acc 64 = 124 <= 128,
// 4 blocks/CU (16 waves) for deeper latency hiding on both pipes.
// 1-D grid, xcd-major sibling-adjacent: 4 channel-slices (y) of one m-tile
// dispatch-adjacent on ONE XCD -> A-slice L2-shared (R19: FETCH 258->75MB).
// ---------------------------------------------------------------------------
__global__ __launch_bounds__(256, 4) void gemm1_kernel(
    const bf16* __restrict__ hpad, const bf16* __restrict__ spect,
    const bf16* __restrict__ wx,   // this layer: [44][4][512][8]
    const float* __restrict__ xb,  // [512] combined in_b + cond_b
    bf16* __restrict__ acts, int dil)
{
  // slot (shorts): A [4 kc][128 t][8]=4096, B1 [4][64 n][8]=2048, B2 2048
  __shared__ alignas(16) short lds[2 * 8192];    // 32 KB

  const int tid  = threadIdx.x;
  const int lane = tid & 63;
  const int wid  = tid >> 6;
  const int wm   = wid >> 1;          // 0..1
  const int wn   = wid & 1;           // 0..1

  const int id   = blockIdx.x;        // 2048 blocks
  const int xcd  = id & 7;
  const int seq  = id >> 3;
  const int tile = seq >> 2;          // 0..63
  const int y    = seq & 3;
  const int m0 = (xcd * 64 + tile) * 128;
  const int c0 = y * 64;              // tanh channel tile: 0/64/128/192
  const int b  = m0 >> 12;            // tile fully inside one batch
  const int t0 = m0 & (SEQT - 1);

  const f32x4 fzero = {0.f, 0.f, 0.f, 0.f};
  f32x4 acc1[4][2], acc2[4][2];
#pragma unroll
  for (int i = 0; i < 4; ++i)
#pragma unroll
    for (int j = 0; j < 2; ++j) { acc1[i][j] = fzero; acc2[i][j] = fzero; }

  const int tA  = tid & 127;
  const int ccA = tid >> 7;           // 0..1 -> stages cc=ccA, ccA+2
  const int nB  = tid & 63;
  const int kcB = tid >> 6;           // 0..3

  const bf16* pAh = hpad  + (((size_t)b * 32 + ccA) * TPAD + PADT + t0 + tA) * 8;
  const bf16* pAs = spect + (((size_t)b * 80 + ccA) * 4096 + t0 + tA) * 8;
  const bf16* pB1 = wx + ((size_t)(kcB * 512) + c0 + nB) * 8;
  const bf16* pB2 = pB1 + 2048;       // +256 cols (sigmoid class)
  const ptrdiff_t dil8 = (ptrdiff_t)dil * 8;

  auto stage = [&](int kt) {
    short* base = lds + (kt & 1) * 8192;
    const bf16* a0;
    ptrdiff_t astep;
    if (kt < 24) {
      const int tap = kt >> 3;                       // 0,1,2
      a0 = pAh + (ptrdiff_t)((kt & 7) * 4) * (TPAD * 8) + (ptrdiff_t)(tap - 1) * dil8;
      astep = (ptrdiff_t)2 * TPAD * 8;
    } else {
      a0 = pAs + (ptrdiff_t)(kt - 24) * 131072;      // 4*4096*8
      astep = (ptrdiff_t)2 * 4096 * 8;
    }
    const bf16* w1 = pB1 + (ptrdiff_t)kt * 16384;    // 4*512*8
    const bf16* w2 = pB2 + (ptrdiff_t)kt * 16384;
    g2l16(a0,         base + (ccA * 128 + tA) * 8);
    g2l16(a0 + astep, base + ((ccA + 2) * 128 + tA) * 8);
    g2l16(w1,         base + 4096 + (kcB * 64 + nB) * 8);
    g2l16(w2,         base + 6144 + (kcB * 64 + nB) * 8);
  };

  const int rl = lane & 15;
  const int kc = lane >> 4;           // 0..3

  stage(0);                            // PROLOGUE
  for (int kt = 0; kt < 44; ++kt) {
    if (kt < 43) { stage(kt + 1); VM4(); }
    else         { VM0(); }
    BAR();                             // slot kt&1 fully staged (all waves)

    const short* cur = lds + (kt & 1) * 8192;
    short8 af[4], bfa[2], bfb[2];
#pragma unroll
    for (int f = 0; f < 4; ++f)
      af[f]  = *(const short8*)(cur + (kc * 128 + wm * 64 + f * 16 + rl) * 8);
#pragma unroll
    for (int j = 0; j < 2; ++j) {
      bfa[j] = *(const short8*)(cur + 4096 + (kc * 64 + wn * 32 + j * 16 + rl) * 8);
      bfb[j] = *(const short8*)(cur + 6144 + (kc * 64 + wn * 32 + j * 16 + rl) * 8);
    }
    LGKM0();
    SB0();
    BAR();                             // all reads of slot kt&1 retired
    __builtin_amdgcn_s_setprio(1);
#pragma unroll
    for (int i = 0; i < 4; ++i)
#pragma unroll
      for (int j = 0; j < 2; ++j) {
        acc1[i][j] = __builtin_amdgcn_mfma_f32_16x16x32_bf16(af[i], bfa[j], acc1[i][j], 0, 0, 0);
        acc2[i][j] = __builtin_amdgcn_mfma_f32_16x16x32_bf16(af[i], bfb[j], acc2[i][j], 0, 0, 0);
      }
    __builtin_amdgcn_s_setprio(0);
  }

  // ---- epilogue: gate -> LDS bounce [8 cc'][128 t][8] -> coalesced stores
  short* obuf = lds;                   // 16 KB (slot 0; last chunk used slot 1)
  const int rl2 = lane & 15;
  const int ro  = (lane >> 4) * 4;
#pragma unroll
  for (int i = 0; i < 4; ++i) {
#pragma unroll
    for (int j = 0; j < 2; ++j) {
      const int lc = wn * 32 + j * 16 + rl2;         // local tanh ch 0..63
      const float bx1 = xb[c0 + lc];
      const float bx2 = xb[c0 + lc + 256];
#pragma unroll
      for (int r = 0; r < 4; ++r) {
        const int t = wm * 64 + i * 16 + ro + r;     // 0..127
        const float x1 = acc1[i][j][r] + bx1;
        const float x2 = acc2[i][j][r] + bx2;
        obuf[((lc >> 3) * 128 + t) * 8 + (lc & 7)] = f2bf_s(ftanh_(x1) * fsigmoid(x2));
      }
    }
  }
  __syncthreads();
  const int tt = tid & 127;
  const int c2 = tid >> 7;            // 0..1
  short* ag = (short*)acts;
#pragma unroll
  for (int q = 0; q < 4; ++q) {
    const int ccp = c2 * 4 + q;       // 0..7
    const short8 v = *(const short8*)(obuf + (ccp * 128 + tt) * 8);
    *(short8*)(ag + ((size_t)(b * 32 + (c0 >> 3) + ccp) * 4096 + t0 + tt) * 8) = v;
  }
}

// ---------------------------------------------------------------------------
// GEMM2: rs = acts @ Wr^T (+rb); n-half 0 -> h += rs ; half 1 -> skip += rs
// R13 structure + R15 coalesced epilogues. NEW: 1-D xcd-major grid, the two
// n-halves of one m-tile dispatch-adjacent on one XCD (acts L2-shared).
//   id: xcd = id&7 ; seq = id>>3 ; tile = seq>>1 (0..127) ; half = seq&1
//   m0 = (xcd*128 + tile)*64 ; n0 = half*256
// ---------------------------------------------------------------------------
__global__ __launch_bounds__(256, 3) void gemm2_kernel(
    const bf16* __restrict__ acts, const bf16* __restrict__ wr,  // [8][4][512][8]
    const float* __restrict__ rb, bf16* __restrict__ hpad,
    bf16* __restrict__ skip, const int first)
{
  // slot (shorts): A [4 kc][64 t][8]=2048, B [4 kc][256 n][8]=8192
  __shared__ alignas(16) short lds[2 * 10240];   // 40 KB (obuf needs 32 KB)

  const int tid  = threadIdx.x;
  const int lane = tid & 63;
  const int wid  = tid >> 6;
  const int wm   = wid >> 1;          // 0..1
  const int wn   = wid & 1;           // 0..1

  const int id   = blockIdx.x;        // 2048 blocks
  const int xcd  = id & 7;
  const int seq  = id >> 3;
  const int tile = seq >> 1;          // 0..127
  const int half = seq & 1;
  const int m0 = (xcd * 128 + tile) * 64;
  const int n0 = half * 256;          // 0 (h-update) or 256 (skip)
  const int b  = m0 >> 12;
  const int t0 = m0 & (SEQT - 1);

  const f32x4 fzero = {0.f, 0.f, 0.f, 0.f};
  f32x4 acc[2][8];
#pragma unroll
  for (int i = 0; i < 2; ++i)
#pragma unroll
    for (int j = 0; j < 8; ++j) acc[i][j] = fzero;

  const int tA  = tid & 63;
  const int ccA = tid >> 6;           // 0..3

  const bf16* pA = acts + (((size_t)b * 32 + ccA) * 4096 + t0 + tA) * 8;
  const bf16* pB = wr + ((size_t)n0 + tid) * 8;    // col n0+tid, all 4 kc

  auto stage = [&](int kt) {
    short* base = lds + (kt & 1) * 10240;
    const bf16* a0 = pA + (ptrdiff_t)kt * 131072;  // 4*4096*8
    const bf16* w0 = pB + (ptrdiff_t)kt * 16384;   // 4*512*8
    g2l16(a0, base + (ccA * 64 + tA) * 8);
#pragma unroll
    for (int kcq = 0; kcq < 4; ++kcq)
      g2l16(w0 + kcq * 4096, base + 2048 + (kcq * 256 + tid) * 8);
  };

  const int rl = lane & 15;
  const int kc = lane >> 4;

  stage(0);                            // PROLOGUE
  for (int kt = 0; kt < 8; ++kt) {
    if (kt < 7) { stage(kt + 1); VM5(); }
    else        { VM0(); }
    BAR();

    const short* cur = lds + (kt & 1) * 10240;
    short8 af[2], bfr[8];
#pragma unroll
    for (int f = 0; f < 2; ++f)
      af[f] = *(const short8*)(cur + (kc * 64 + wm * 32 + f * 16 + rl) * 8);
#pragma unroll
    for (int j = 0; j < 8; ++j)
      bfr[j] = *(const short8*)(cur + 2048 + (kc * 256 + wn * 128 + j * 16 + rl) * 8);
    LGKM0();
    SB0();
    BAR();
    __builtin_amdgcn_s_setprio(1);
#pragma unroll
    for (int i = 0; i < 2; ++i)
#pragma unroll
      for (int j = 0; j < 8; ++j)
        acc[i][j] = __builtin_amdgcn_mfma_f32_16x16x32_bf16(af[i], bfr[j], acc[i][j], 0, 0, 0);
    __builtin_amdgcn_s_setprio(0);
  }

  // ---- epilogue: rs+bias -> LDS bounce -> coalesced RMW
  short* obuf = lds;
  const int rl2 = lane & 15;
  const int ro  = (lane >> 4) * 4;
  if (n0 == 0) {
    // h-update: obuf NC8 [32 cc][64 t][8] = 32 KB
#pragma unroll
    for (int i = 0; i < 2; ++i) {
#pragma unroll
      for (int j = 0; j < 8; ++j) {
        const int n = wn * 128 + j * 16 + rl2;       // 0..255
        const float bias = rb[n];
#pragma unroll
        for (int r = 0; r < 4; ++r) {
          const int t = wm * 32 + i * 16 + ro + r;
          obuf[((n >> 3) * 64 + t) * 8 + (n & 7)] = f2bf_s(acc[i][j][r] + bias);
        }
      }
    }
    __syncthreads();
    const int tt = tid & 63;
    const int c4 = tid >> 6;
    short* hg = (short*)hpad;
#pragma unroll
    for (int q = 0; q < 8; ++q) {
      const int cc = c4 * 8 + q;                     // 0..31
      const size_t gi = (((size_t)b * 32 + cc) * TPAD + PADT + t0 + tt) * 8;
      short8 hv = *(const short8*)(hg + gi);
      const short8 rv = *(const short8*)(obuf + (cc * 64 + tt) * 8);
      short8 ov;
#pragma unroll
      for (int w = 0; w < 8; ++w)
        ov[w] = f2bf_s(bf2f((unsigned short)hv[w]) + bf2f((unsigned short)rv[w]));
      *(short8*)(hg + gi) = ov;
    }
  } else {
    // skip: obuf row-major [64 t][256 n] = 32 KB
#pragma unroll
    for (int i = 0; i < 2; ++i) {
#pragma unroll
      for (int j = 0; j < 8; ++j) {
        const int n = wn * 128 + j * 16 + rl2;       // 0..255
        const float bias = rb[256 + n];
#pragma unroll
        for (int r = 0; r < 4; ++r) {
          const int t = wm * 32 + i * 16 + ro + r;
          obuf[t * 256 + n] = f2bf_s(acc[i][j][r] + bias);
        }
      }
    }
    __syncthreads();
    short* sg = (short*)skip;
#pragma unroll
    for (int q = 0; q < 8; ++q) {
      const int idx = q * 256 + tid;                 // 0..2047 chunks
      const int t  = idx >> 5;
      const int nc = idx & 31;
      const size_t gi = ((size_t)(b * SEQT + t0 + t)) * NCH + nc * 8;
      const short8 rv = *(const short8*)(obuf + t * 256 + nc * 8);
      if (first) {
        *(short8*)(sg + gi) = rv;
      } else {
        short8 sv = *(const short8*)(sg + gi);
        short8 ov;
#pragma unroll
        for (int w = 0; w < 8; ++w)
          ov[w] = f2bf_s(bf2f((unsigned short)sv[w]) + bf2f((unsigned short)rv[w]));
        *(short8*)(sg + gi) = ov;
      }
    }
  }
}

// ---------------------------------------------------------------------------
// aux kernels
// ---------------------------------------------------------------------------
__global__ void start_kernel(const float* __restrict__ audio, const float* __restrict__ sw,
                             const float* __restrict__ sb, bf16* __restrict__ hpad)
{
  const int idx = blockIdx.x * 256 + threadIdx.x;   // < 16777216
  const int w  = idx & 7;
  const int t  = (idx >> 3) & 4095;
  const int cc = (idx >> 15) & 31;
  const int b  = idx >> 20;
  const int c  = cc * 8 + w;
  const float* a = audio + ((size_t)(b * SEQT + t)) * 4;
  float v = sb[c] + a[0] * sw[c] + a[1] * sw[256 + c] + a[2] * sw[512 + c] + a[3] * sw[768 + c];
  hpad[(((size_t)b * 32 + cc) * TPAD + PADT + t) * 8 + w] = __float2bfloat16(v);
}

__global__ void cvt_spect_kernel(const float* __restrict__ s, bf16* __restrict__ d)
{
  const size_t idx = (size_t)blockIdx.x * 256 + threadIdx.x;  // < 41943040
  const int w  = (int)(idx & 7);
  const int t  = (int)((idx >> 3) & 4095);
  const unsigned q = (unsigned)(idx >> 15);     // b*80 + cc
  const int b  = q / 80;
  const int cc = q % 80;
  const int c  = cc * 8 + w;
  d[idx] = __float2bfloat16(s[((size_t)(b * SEQT + t)) * NMEL + c]);
}

__global__ void prep_wx_kernel(const float* __restrict__ in_w, const float* __restrict__ cond_w,
                               bf16* __restrict__ wx)
{
  const size_t idx = (size_t)blockIdx.x * 256 + threadIdx.x;
  if (idx >= (size_t)LAYERS * 44 * 4 * 512 * 8) return;
  const int w   = (int)(idx & 7);
  const int n   = (int)((idx >> 3) & 511);
  const int kc  = (int)((idx >> 12) & 3);
  const unsigned ktp = (unsigned)(idx >> 14);   // i*44 + kt
  const int i  = ktp / 44;
  const int kt = ktp % 44;
  const int k  = kt * 32 + kc * 8 + w;
  float v;
  if (k < 768) {
    const int tap = k >> 8;
    const int c   = k & 255;
    v = in_w[(size_t)(((i * 3 + tap) << 8) + c) * 512 + n];
  } else {
    v = cond_w[((size_t)i * NMEL + (k - 768)) * 512 + n];
  }
  wx[idx] = __float2bfloat16(v);
}

__global__ void prep_wr_kernel(const float* __restrict__ rs_w, const float* __restrict__ rs_w_last,
                               bf16* __restrict__ wr)
{
  const int idx = blockIdx.x * 256 + threadIdx.x;   // < 1048576
  const int w  = idx & 7;
  const int n  = (idx >> 3) & 511;
  const int kc = (idx >> 12) & 3;
  const int kt = (idx >> 14) & 7;
  const int i  = idx >> 17;
  const int k  = kt * 32 + kc * 8 + w;              // [0,256)
  float v;
  if (i < LAYERS - 1) v = rs_w[(size_t)((i << 8) + k) * 512 + n];
  else                v = (n >= 256) ? rs_w_last[(k << 8) + (n - 256)] : 0.f;
  wr[idx] = __float2bfloat16(v);
}

__global__ void prep_bias_kernel(const float* __restrict__ in_b, const float* __restrict__ cond_b,
                                 const float* __restrict__ rs_b, const float* __restrict__ rs_b_last,
                                 float* __restrict__ xb, float* __restrict__ rb)
{
  const int idx = blockIdx.x * 256 + threadIdx.x;   // < 4096
  if (idx >= LAYERS * 512) return;
  const int i = idx >> 9;
  const int n = idx & 511;
  xb[idx] = in_b[idx] + cond_b[idx];
  rb[idx] = (i < LAYERS - 1) ? rs_b[idx] : ((n >= 256) ? rs_b_last[n - 256] : 0.f);
}

__global__ void end_kernel(const bf16* __restrict__ skip, const float* __restrict__ ew,
                           const float* __restrict__ eb, float* __restrict__ out)
{
  const int idx = blockIdx.x * 256 + threadIdx.x;   // < 524288
  const int m = idx >> 3;
  const int j = idx & 7;
  const bf16* srow = skip + (size_t)m * NCH;
  float s = eb[j];
#pragma unroll 4
  for (int c8 = 0; c8 < NCH / 8; ++c8) {
    short8 v = *(const short8*)(srow + c8 * 8);
#pragma unroll
    for (int w = 0; w < 8; ++w)
      s += bf2f((unsigned short)v[w]) * ew[(c8 * 8 + w) * 8 + j];
  }
  out[idx] = s;
}

// ---------------------------------------------------------------------------
extern "C" void kernel_launch(void* const* d_in, const int* in_sizes, int n_in,
                              void* d_out, int out_size, void* d_ws, size_t ws_size,
                              hipStream_t stream)
{
  const float* audio     = (const float*)d_in[0];
  const float* spect     = (const float*)d_in[1];
  const float* start_w   = (const float*)d_in[2];
  const float* start_b   = (const float*)d_in[3];
  const float* in_w      = (const float*)d_in[4];
  const float* in_b      = (const float*)d_in[5];
  const float* cond_w    = (const float*)d_in[6];
  const float* cond_b    = (const float*)d_in[7];
  const float* rs_w      = (const float*)d_in[8];
  const float* rs_b      = (const float*)d_in[9];
  const float* rs_w_last = (const float*)d_in[10];
  const float* rs_b_last = (const float*)d_in[11];
  const float* end_w     = (const float*)d_in[12];
  const float* end_b     = (const float*)d_in[13];
  float* out = (float*)d_out;

  char* p = (char*)d_ws;
  bf16* spect_bf = (bf16*)p;  p += (size_t)BTROWS * NMEL * 2;          // 83.9 MB
  bf16* hpad     = (bf16*)p;  p += (size_t)NBATCH * 32 * TPAD * 8 * 2; // 35.7 MB
  bf16* actsb    = (bf16*)p;  p += (size_t)BTROWS * NCH * 2;           // 33.6 MB
  bf16* skip     = (bf16*)p;  p += (size_t)BTROWS * NCH * 2;           // 33.6 MB
  bf16* wx       = (bf16*)p;  p += (size_t)LAYERS * 512 * KX * 2;      // 11.5 MB
  bf16* wr       = (bf16*)p;  p += (size_t)LAYERS * 512 * 256 * 2;     //  2.1 MB
  float* xb      = (float*)p; p += (size_t)LAYERS * 512 * 4;
  float* rb      = (float*)p; p += (size_t)LAYERS * 512 * 4;
  if ((size_t)(p - (char*)d_ws) > ws_size) return;  // insufficient workspace

  hipMemsetAsync(hpad, 0, (size_t)NBATCH * 32 * TPAD * 8 * 2, stream);
  prep_wx_kernel<<<(LAYERS * 512 * KX + 255) / 256, 256, 0, stream>>>(in_w, cond_w, wx);
  prep_wr_kernel<<<(LAYERS * 512 * 256) / 256, 256, 0, stream>>>(rs_w, rs_w_last, wr);
  prep_bias_kernel<<<16, 256, 0, stream>>>(in_b, cond_b, rs_b, rs_b_last, xb, rb);
  cvt_spect_kernel<<<(BTROWS * NMEL) / 256, 256, 0, stream>>>(spect, spect_bf);
  start_kernel<<<(BTROWS * NCH) / 256, 256, 0, stream>>>(audio, start_w, start_b, hpad);

  for (int i = 0; i < LAYERS; ++i) {
    gemm1_kernel<<<2048, 256, 0, stream>>>(hpad, spect_bf, wx + (size_t)i * 44 * 4 * 512 * 8,
                                           xb + i * 512, actsb, 1 << i);
    gemm2_kernel<<<2048, 256, 0, stream>>>(actsb, wr + (size_t)i * 8 * 4 * 512 * 8,
                                           rb + i * 512, hpad, skip, i == 0 ? 1 : 0);
  }
  end_kernel<<<(BTROWS * 8) / 256, 256, 0, stream>>>(skip, end_w, end_b, out);
}

// Round 21
// 1135.929 us; speedup vs baseline: 1.1668x; 1.0359x over previous
//
#include <hip/hip_runtime.h>
#include <hip/hip_bf16.h>
#include <stdint.h>
#include <stddef.h>

#define LAYERS 8
#define NCH 256
#define NMEL 640
#define NBATCH 16
#define SEQT 4096
#define BTROWS (NBATCH * SEQT)   // 65536
#define PADT 128
#define TPAD (SEQT + 2 * PADT)   // 4352
#define KX 1408                  // 3*256 + 640

// NC8 layouts (all bf16, inner dim = 8 channels/k):
//  hpad : [b][32 cc][TPAD t][8]
//  spect: [b][80 cc][4096 t][8]
//  acts : [b][32 cc][4096 t][8]
//  wx   : [layer][44 kt][4 kc][512 n][8]
//  wr   : [layer][ 8 kt][4 kc][512 n][8]
//  skip : [m][256]  (row-major, feeds end_kernel)

typedef __hip_bfloat16 bf16;
typedef __attribute__((ext_vector_type(8))) short short8;
typedef __attribute__((ext_vector_type(4))) short short4v;
typedef __attribute__((ext_vector_type(4))) float f32x4;

__device__ __forceinline__ void g2l16(const void* g, void* l) {
  __builtin_amdgcn_global_load_lds(
      (const __attribute__((address_space(1))) unsigned int*)g,
      (__attribute__((address_space(3))) unsigned int*)l, 16, 0, 0);
}

#define VM4()   asm volatile("s_waitcnt vmcnt(4)"  ::: "memory")
#define VM5()   asm volatile("s_waitcnt vmcnt(5)"  ::: "memory")
#define VM0()   asm volatile("s_waitcnt vmcnt(0)"  ::: "memory")
#define LGKM0() asm volatile("s_waitcnt lgkmcnt(0)" ::: "memory")
#define SB0()   __builtin_amdgcn_sched_barrier(0)
#define BAR()   __builtin_amdgcn_s_barrier()

__device__ __forceinline__ float fsigmoid(float x) { return 1.f / (1.f + __expf(-x)); }
__device__ __forceinline__ float ftanh_(float x) { return 1.f - 2.f / (__expf(2.f * x) + 1.f); }
__device__ __forceinline__ float bf2f(unsigned short u) {
  unsigned x = ((unsigned)u) << 16; float f; __builtin_memcpy(&f, &x, 4); return f;
}
__device__ __forceinline__ short f2bf_s(float x) {
  bf16 v = __float2bfloat16(x); short s; __builtin_memcpy(&s, &v, 2); return s;
}

// ---------------------------------------------------------------------------
// GEMM1: x = [h(t-d);h(t);h(t+d);spect] @ Wstack^T ; acts = tanh(x1)*sig(x2)
// R19 structure. 1-D grid, xcd-major sibling-adjacent: 4 channel-slices (y)
// of one m-tile dispatch-adjacent on ONE XCD -> A-slice L2-shared.
// ---------------------------------------------------------------------------
__global__ __launch_bounds__(256, 4) void gemm1_kernel(
    const bf16* __restrict__ hpad, const bf16* __restrict__ spect,
    const bf16* __restrict__ wx,   // this layer: [44][4][512][8]
    const float* __restrict__ xb,  // [512] combined in_b + cond_b
    bf16* __restrict__ acts, int dil)
{
  // slot (shorts): A [4 kc][128 t][8]=4096, B1 [4][64 n][8]=2048, B2 2048
  __shared__ alignas(16) short lds[2 * 8192];    // 32 KB

  const int tid  = threadIdx.x;
  const int lane = tid & 63;
  const int wid  = tid >> 6;
  const int wm   = wid >> 1;          // 0..1
  const int wn   = wid & 1;           // 0..1

  const int id   = blockIdx.x;        // 2048 blocks
  const int xcd  = id & 7;
  const int seq  = id >> 3;
  const int tile = seq >> 2;          // 0..63
  const int y    = seq & 3;
  const int m0 = (xcd * 64 + tile) * 128;
  const int c0 = y * 64;              // tanh channel tile: 0/64/128/192
  const int b  = m0 >> 12;            // tile fully inside one batch
  const int t0 = m0 & (SEQT - 1);

  const f32x4 fzero = {0.f, 0.f, 0.f, 0.f};
  f32x4 acc1[4][2], acc2[4][2];
#pragma unroll
  for (int i = 0; i < 4; ++i)
#pragma unroll
    for (int j = 0; j < 2; ++j) { acc1[i][j] = fzero; acc2[i][j] = fzero; }

  const int tA  = tid & 127;
  const int ccA = tid >> 7;           // 0..1 -> stages cc=ccA, ccA+2
  const int nB  = tid & 63;
  const int kcB = tid >> 6;           // 0..3

  const bf16* pAh = hpad  + (((size_t)b * 32 + ccA) * TPAD + PADT + t0 + tA) * 8;
  const bf16* pAs = spect + (((size_t)b * 80 + ccA) * 4096 + t0 + tA) * 8;
  const bf16* pB1 = wx + ((size_t)(kcB * 512) + c0 + nB) * 8;
  const bf16* pB2 = pB1 + 2048;       // +256 cols (sigmoid class)
  const ptrdiff_t dil8 = (ptrdiff_t)dil * 8;

  auto stage = [&](int kt) {
    short* base = lds + (kt & 1) * 8192;
    const bf16* a0;
    ptrdiff_t astep;
    if (kt < 24) {
      const int tap = kt >> 3;                       // 0,1,2
      a0 = pAh + (ptrdiff_t)((kt & 7) * 4) * (TPAD * 8) + (ptrdiff_t)(tap - 1) * dil8;
      astep = (ptrdiff_t)2 * TPAD * 8;
    } else {
      a0 = pAs + (ptrdiff_t)(kt - 24) * 131072;      // 4*4096*8
      astep = (ptrdiff_t)2 * 4096 * 8;
    }
    const bf16* w1 = pB1 + (ptrdiff_t)kt * 16384;    // 4*512*8
    const bf16* w2 = pB2 + (ptrdiff_t)kt * 16384;
    g2l16(a0,         base + (ccA * 128 + tA) * 8);
    g2l16(a0 + astep, base + ((ccA + 2) * 128 + tA) * 8);
    g2l16(w1,         base + 4096 + (kcB * 64 + nB) * 8);
    g2l16(w2,         base + 6144 + (kcB * 64 + nB) * 8);
  };

  const int rl = lane & 15;
  const int kc = lane >> 4;           // 0..3

  stage(0);                            // PROLOGUE
  for (int kt = 0; kt < 44; ++kt) {
    if (kt < 43) { stage(kt + 1); VM4(); }
    else         { VM0(); }
    BAR();                             // slot kt&1 fully staged (all waves)

    const short* cur = lds + (kt & 1) * 8192;
    short8 af[4], bfa[2], bfb[2];
#pragma unroll
    for (int f = 0; f < 4; ++f)
      af[f]  = *(const short8*)(cur + (kc * 128 + wm * 64 + f * 16 + rl) * 8);
#pragma unroll
    for (int j = 0; j < 2; ++j) {
      bfa[j] = *(const short8*)(cur + 4096 + (kc * 64 + wn * 32 + j * 16 + rl) * 8);
      bfb[j] = *(const short8*)(cur + 6144 + (kc * 64 + wn * 32 + j * 16 + rl) * 8);
    }
    LGKM0();
    SB0();
    BAR();                             // all reads of slot kt&1 retired
    __builtin_amdgcn_s_setprio(1);
#pragma unroll
    for (int i = 0; i < 4; ++i)
#pragma unroll
      for (int j = 0; j < 2; ++j) {
        acc1[i][j] = __builtin_amdgcn_mfma_f32_16x16x32_bf16(af[i], bfa[j], acc1[i][j], 0, 0, 0);
        acc2[i][j] = __builtin_amdgcn_mfma_f32_16x16x32_bf16(af[i], bfb[j], acc2[i][j], 0, 0, 0);
      }
    __builtin_amdgcn_s_setprio(0);
  }

  // ---- epilogue: gate -> LDS bounce [8 cc'][128 t][8] -> coalesced stores
  short* obuf = lds;                   // 16 KB (slot 0; last chunk used slot 1)
  const int rl2 = lane & 15;
  const int ro  = (lane >> 4) * 4;
#pragma unroll
  for (int i = 0; i < 4; ++i) {
#pragma unroll
    for (int j = 0; j < 2; ++j) {
      const int lc = wn * 32 + j * 16 + rl2;         // local tanh ch 0..63
      const float bx1 = xb[c0 + lc];
      const float bx2 = xb[c0 + lc + 256];
#pragma unroll
      for (int r = 0; r < 4; ++r) {
        const int t = wm * 64 + i * 16 + ro + r;     // 0..127
        const float x1 = acc1[i][j][r] + bx1;
        const float x2 = acc2[i][j][r] + bx2;
        obuf[((lc >> 3) * 128 + t) * 8 + (lc & 7)] = f2bf_s(ftanh_(x1) * fsigmoid(x2));
      }
    }
  }
  __syncthreads();
  const int tt = tid & 127;
  const int c2 = tid >> 7;            // 0..1
  short* ag = (short*)acts;
#pragma unroll
  for (int q = 0; q < 4; ++q) {
    const int ccp = c2 * 4 + q;       // 0..7
    const short8 v = *(const short8*)(obuf + (ccp * 128 + tt) * 8);
    *(short8*)(ag + ((size_t)(b * 32 + (c0 >> 3) + ccp) * 4096 + t0 + tt) * 8) = v;
  }
}

// ---------------------------------------------------------------------------
// GEMM2: rs = acts @ Wr^T (+rb); n-half 0 -> h += rs ; half 1 -> skip += rs
// R13 structure + R15 coalesced epilogues + xcd-major sibling-adjacent grid.
// ---------------------------------------------------------------------------
__global__ __launch_bounds__(256, 3) void gemm2_kernel(
    const bf16* __restrict__ acts, const bf16* __restrict__ wr,  // [8][4][512][8]
    const float* __restrict__ rb, bf16* __restrict__ hpad,
    bf16* __restrict__ skip, const int first)
{
  // slot (shorts): A [4 kc][64 t][8]=2048, B [4 kc][256 n][8]=8192
  __shared__ alignas(16) short lds[2 * 10240];   // 40 KB (obuf needs 32 KB)

  const int tid  = threadIdx.x;
  const int lane = tid & 63;
  const int wid  = tid >> 6;
  const int wm   = wid >> 1;          // 0..1
  const int wn   = wid & 1;           // 0..1

  const int id   = blockIdx.x;        // 2048 blocks
  const int xcd  = id & 7;
  const int seq  = id >> 3;
  const int tile = seq >> 1;          // 0..127
  const int half = seq & 1;
  const int m0 = (xcd * 128 + tile) * 64;
  const int n0 = half * 256;          // 0 (h-update) or 256 (skip)
  const int b  = m0 >> 12;
  const int t0 = m0 & (SEQT - 1);

  const f32x4 fzero = {0.f, 0.f, 0.f, 0.f};
  f32x4 acc[2][8];
#pragma unroll
  for (int i = 0; i < 2; ++i)
#pragma unroll
    for (int j = 0; j < 8; ++j) acc[i][j] = fzero;

  const int tA  = tid & 63;
  const int ccA = tid >> 6;           // 0..3

  const bf16* pA = acts + (((size_t)b * 32 + ccA) * 4096 + t0 + tA) * 8;
  const bf16* pB = wr + ((size_t)n0 + tid) * 8;    // col n0+tid, all 4 kc

  auto stage = [&](int kt) {
    short* base = lds + (kt & 1) * 10240;
    const bf16* a0 = pA + (ptrdiff_t)kt * 131072;  // 4*4096*8
    const bf16* w0 = pB + (ptrdiff_t)kt * 16384;   // 4*512*8
    g2l16(a0, base + (ccA * 64 + tA) * 8);
#pragma unroll
    for (int kcq = 0; kcq < 4; ++kcq)
      g2l16(w0 + kcq * 4096, base + 2048 + (kcq * 256 + tid) * 8);
  };

  const int rl = lane & 15;
  const int kc = lane >> 4;

  stage(0);                            // PROLOGUE
  for (int kt = 0; kt < 8; ++kt) {
    if (kt < 7) { stage(kt + 1); VM5(); }
    else        { VM0(); }
    BAR();

    const short* cur = lds + (kt & 1) * 10240;
    short8 af[2], bfr[8];
#pragma unroll
    for (int f = 0; f < 2; ++f)
      af[f] = *(const short8*)(cur + (kc * 64 + wm * 32 + f * 16 + rl) * 8);
#pragma unroll
    for (int j = 0; j < 8; ++j)
      bfr[j] = *(const short8*)(cur + 2048 + (kc * 256 + wn * 128 + j * 16 + rl) * 8);
    LGKM0();
    SB0();
    BAR();
    __builtin_amdgcn_s_setprio(1);
#pragma unroll
    for (int i = 0; i < 2; ++i)
#pragma unroll
      for (int j = 0; j < 8; ++j)
        acc[i][j] = __builtin_amdgcn_mfma_f32_16x16x32_bf16(af[i], bfr[j], acc[i][j], 0, 0, 0);
    __builtin_amdgcn_s_setprio(0);
  }

  // ---- epilogue: rs+bias -> LDS bounce -> coalesced RMW
  short* obuf = lds;
  const int rl2 = lane & 15;
  const int ro  = (lane >> 4) * 4;
  if (n0 == 0) {
    // h-update: obuf NC8 [32 cc][64 t][8] = 32 KB
#pragma unroll
    for (int i = 0; i < 2; ++i) {
#pragma unroll
      for (int j = 0; j < 8; ++j) {
        const int n = wn * 128 + j * 16 + rl2;       // 0..255
        const float bias = rb[n];
#pragma unroll
        for (int r = 0; r < 4; ++r) {
          const int t = wm * 32 + i * 16 + ro + r;
          obuf[((n >> 3) * 64 + t) * 8 + (n & 7)] = f2bf_s(acc[i][j][r] + bias);
        }
      }
    }
    __syncthreads();
    const int tt = tid & 63;
    const int c4 = tid >> 6;
    short* hg = (short*)hpad;
#pragma unroll
    for (int q = 0; q < 8; ++q) {
      const int cc = c4 * 8 + q;                     // 0..31
      const size_t gi = (((size_t)b * 32 + cc) * TPAD + PADT + t0 + tt) * 8;
      short8 hv = *(const short8*)(hg + gi);
      const short8 rv = *(const short8*)(obuf + (cc * 64 + tt) * 8);
      short8 ov;
#pragma unroll
      for (int w = 0; w < 8; ++w)
        ov[w] = f2bf_s(bf2f((unsigned short)hv[w]) + bf2f((unsigned short)rv[w]));
      *(short8*)(hg + gi) = ov;
    }
  } else {
    // skip: obuf row-major [64 t][256 n] = 32 KB
#pragma unroll
    for (int i = 0; i < 2; ++i) {
#pragma unroll
      for (int j = 0; j < 8; ++j) {
        const int n = wn * 128 + j * 16 + rl2;       // 0..255
        const float bias = rb[256 + n];
#pragma unroll
        for (int r = 0; r < 4; ++r) {
          const int t = wm * 32 + i * 16 + ro + r;
          obuf[t * 256 + n] = f2bf_s(acc[i][j][r] + bias);
        }
      }
    }
    __syncthreads();
    short* sg = (short*)skip;
#pragma unroll
    for (int q = 0; q < 8; ++q) {
      const int idx = q * 256 + tid;                 // 0..2047 chunks
      const int t  = idx >> 5;
      const int nc = idx & 31;
      const size_t gi = ((size_t)(b * SEQT + t0 + t)) * NCH + nc * 8;
      const short8 rv = *(const short8*)(obuf + t * 256 + nc * 8);
      if (first) {
        *(short8*)(sg + gi) = rv;
      } else {
        short8 sv = *(const short8*)(sg + gi);
        short8 ov;
#pragma unroll
        for (int w = 0; w < 8; ++w)
          ov[w] = f2bf_s(bf2f((unsigned short)sv[w]) + bf2f((unsigned short)rv[w]));
        *(short8*)(sg + gi) = ov;
      }
    }
  }
}

// ---------------------------------------------------------------------------
// aux kernels
// ---------------------------------------------------------------------------
__global__ void start_kernel(const float* __restrict__ audio, const float* __restrict__ sw,
                             const float* __restrict__ sb, bf16* __restrict__ hpad)
{
  const int idx = blockIdx.x * 256 + threadIdx.x;   // < 16777216
  const int w  = idx & 7;
  const int t  = (idx >> 3) & 4095;
  const int cc = (idx >> 15) & 31;
  const int b  = idx >> 20;
  const int c  = cc * 8 + w;
  const float* a = audio + ((size_t)(b * SEQT + t)) * 4;
  float v = sb[c] + a[0] * sw[c] + a[1] * sw[256 + c] + a[2] * sw[512 + c] + a[3] * sw[768 + c];
  hpad[(((size_t)b * 32 + cc) * TPAD + PADT + t) * 8 + w] = __float2bfloat16(v);
}

// cvt_spect: tiled LDS-bounce transpose. Block = (b, 8 t, 128 c).
// Phase 1: coalesced float4 row reads (32 lanes x 16B = 512B/row) -> bf16 LDS.
// Phase 2: NC8 short4 writes in 128B-contiguous lane groups.
__global__ void cvt_spect_kernel(const float* __restrict__ s, bf16* __restrict__ d)
{
  __shared__ short tile[1024];        // [8 t][128 c] bf16
  const int bid  = blockIdx.x;        // 40960 = 16 b * 512 t-tiles * 5 c-tiles
  const int ct   = bid % 5;
  const int rest = bid / 5;
  const int tt   = rest & 511;
  const int b    = rest >> 9;
  const int c0   = ct * 128;
  const int t0   = tt * 8;
  const int tid  = threadIdx.x;

  // phase 1: read [8][128] f32, convert
  const int cl = tid & 31;            // float4 index in row
  const int tr = tid >> 5;            // 0..7
  const float4 v = *(const float4*)(s + ((size_t)(b * SEQT + t0 + tr)) * NMEL + c0 + cl * 4);
  short* tp = tile + tr * 128 + cl * 4;
  tp[0] = f2bf_s(v.x); tp[1] = f2bf_s(v.y); tp[2] = f2bf_s(v.z); tp[3] = f2bf_s(v.w);
  __syncthreads();

  // phase 2: write NC8 short4s
  const int half = tid & 1;
  const int tr2  = (tid >> 1) & 7;
  const int ccl  = tid >> 4;          // 0..15
  const short4v o = *(const short4v*)(tile + tr2 * 128 + ccl * 8 + half * 4);
  *(short4v*)((short*)d + (((size_t)b * 80 + (c0 >> 3) + ccl) * 4096 + t0 + tr2) * 8 + half * 4) = o;
}

__global__ void prep_wx_kernel(const float* __restrict__ in_w, const float* __restrict__ cond_w,
                               bf16* __restrict__ wx)
{
  const size_t idx = (size_t)blockIdx.x * 256 + threadIdx.x;
  if (idx >= (size_t)LAYERS * 44 * 4 * 512 * 8) return;
  const int w   = (int)(idx & 7);
  const int n   = (int)((idx >> 3) & 511);
  const int kc  = (int)((idx >> 12) & 3);
  const unsigned ktp = (unsigned)(idx >> 14);   // i*44 + kt
  const int i  = ktp / 44;
  const int kt = ktp % 44;
  const int k  = kt * 32 + kc * 8 + w;
  float v;
  if (k < 768) {
    const int tap = k >> 8;
    const int c   = k & 255;
    v = in_w[(size_t)(((i * 3 + tap) << 8) + c) * 512 + n];
  } else {
    v = cond_w[((size_t)i * NMEL + (k - 768)) * 512 + n];
  }
  wx[idx] = __float2bfloat16(v);
}

__global__ void prep_wr_kernel(const float* __restrict__ rs_w, const float* __restrict__ rs_w_last,
                               bf16* __restrict__ wr)
{
  const int idx = blockIdx.x * 256 + threadIdx.x;   // < 1048576
  const int w  = idx & 7;
  const int n  = (idx >> 3) & 511;
  const int kc = (idx >> 12) & 3;
  const int kt = (idx >> 14) & 7;
  const int i  = idx >> 17;
  const int k  = kt * 32 + kc * 8 + w;              // [0,256)
  float v;
  if (i < LAYERS - 1) v = rs_w[(size_t)((i << 8) + k) * 512 + n];
  else                v = (n >= 256) ? rs_w_last[(k << 8) + (n - 256)] : 0.f;
  wr[idx] = __float2bfloat16(v);
}

__global__ void prep_bias_kernel(const float* __restrict__ in_b, const float* __restrict__ cond_b,
                                 const float* __restrict__ rs_b, const float* __restrict__ rs_b_last,
                                 float* __restrict__ xb, float* __restrict__ rb)
{
  const int idx = blockIdx.x * 256 + threadIdx.x;   // < 4096
  if (idx >= LAYERS * 512) return;
  const int i = idx >> 9;
  const int n = idx & 511;
  xb[idx] = in_b[idx] + cond_b[idx];
  rb[idx] = (i < LAYERS - 1) ? rs_b[idx] : ((n >= 256) ? rs_b_last[n - 256] : 0.f);
}

__global__ void end_kernel(const bf16* __restrict__ skip, const float* __restrict__ ew,
                           const float* __restrict__ eb, float* __restrict__ out)
{
  const int idx = blockIdx.x * 256 + threadIdx.x;   // < 524288
  const int m = idx >> 3;
  const int j = idx & 7;
  const bf16* srow = skip + (size_t)m * NCH;
  float s = eb[j];
#pragma unroll 4
  for (int c8 = 0; c8 < NCH / 8; ++c8) {
    short8 v = *(const short8*)(srow + c8 * 8);
#pragma unroll
    for (int w = 0; w < 8; ++w)
      s += bf2f((unsigned short)v[w]) * ew[(c8 * 8 + w) * 8 + j];
  }
  out[idx] = s;
}

// ---------------------------------------------------------------------------
extern "C" void kernel_launch(void* const* d_in, const int* in_sizes, int n_in,
                              void* d_out, int out_size, void* d_ws, size_t ws_size,
                              hipStream_t stream)
{
  const float* audio     = (const float*)d_in[0];
  const float* spect     = (const float*)d_in[1];
  const float* start_w   = (const float*)d_in[2];
  const float* start_b   = (const float*)d_in[3];
  const float* in_w      = (const float*)d_in[4];
  const float* in_b      = (const float*)d_in[5];
  const float* cond_w    = (const float*)d_in[6];
  const float* cond_b    = (const float*)d_in[7];
  const float* rs_w      = (const float*)d_in[8];
  const float* rs_b      = (const float*)d_in[9];
  const float* rs_w_last = (const float*)d_in[10];
  const float* rs_b_last = (const float*)d_in[11];
  const float* end_w     = (const float*)d_in[12];
  const float* end_b     = (const float*)d_in[13];
  float* out = (float*)d_out;

  char* p = (char*)d_ws;
  bf16* spect_bf = (bf16*)p;  p += (size_t)BTROWS * NMEL * 2;          // 83.9 MB
  bf16* hpad     = (bf16*)p;  p += (size_t)NBATCH * 32 * TPAD * 8 * 2; // 35.7 MB
  bf16* actsb    = (bf16*)p;  p += (size_t)BTROWS * NCH * 2;           // 33.6 MB
  bf16* skip     = (bf16*)p;  p += (size_t)BTROWS * NCH * 2;           // 33.6 MB
  bf16* wx       = (bf16*)p;  p += (size_t)LAYERS * 512 * KX * 2;      // 11.5 MB
  bf16* wr       = (bf16*)p;  p += (size_t)LAYERS * 512 * 256 * 2;     //  2.1 MB
  float* xb      = (float*)p; p += (size_t)LAYERS * 512 * 4;
  float* rb      = (float*)p; p += (size_t)LAYERS * 512 * 4;
  if ((size_t)(p - (char*)d_ws) > ws_size) return;  // insufficient workspace

  hipMemsetAsync(hpad, 0, (size_t)NBATCH * 32 * TPAD * 8 * 2, stream);
  prep_wx_kernel<<<(LAYERS * 512 * KX + 255) / 256, 256, 0, stream>>>(in_w, cond_w, wx);
  prep_wr_kernel<<<(LAYERS * 512 * 256) / 256, 256, 0, stream>>>(rs_w, rs_w_last, wr);
  prep_bias_kernel<<<16, 256, 0, stream>>>(in_b, cond_b, rs_b, rs_b_last, xb, rb);
  cvt_spect_kernel<<<40960, 256, 0, stream>>>(spect, spect_bf);
  start_kernel<<<(BTROWS * NCH) / 256, 256, 0, stream>>>(audio, start_w, start_b, hpad);

  for (int i = 0; i < LAYERS; ++i) {
    gemm1_kernel<<<2048, 256, 0, stream>>>(hpad, spect_bf, wx + (size_t)i * 44 * 4 * 512 * 8,
                                           xb + i * 512, actsb, 1 << i);
    gemm2_kernel<<<2048, 256, 0, stream>>>(actsb, wr + (size_t)i * 8 * 4 * 512 * 8,
                                           rb + i * 512, hpad, skip, i == 0 ? 1 : 0);
  }
  end_kernel<<<(BTROWS * 8) / 256, 256, 0, stream>>>(skip, end_w, end_b, out);
}

// Round 22
// 1132.542 us; speedup vs baseline: 1.1703x; 1.0030x over previous
//
#include <hip/hip_runtime.h>
#include <hip/hip_bf16.h>
#include <stdint.h>
#include <stddef.h>

#define LAYERS 8
#define NCH 256
#define NMEL 640
#define NBATCH 16
#define SEQT 4096
#define BTROWS (NBATCH * SEQT)   // 65536
#define PADT 128
#define TPAD (SEQT + 2 * PADT)   // 4352
#define KX 1408                  // 3*256 + 640

// NC8 layouts (all bf16, inner dim = 8 channels/k):
//  hpad : [b][32 cc][TPAD t][8]
//  spect: [b][80 cc][4096 t][8]
//  acts : [b][32 cc][4096 t][8]
//  wx   : [layer][44 kt][4 kc][512 n][8]
//  wr   : [layer][ 8 kt][4 kc][512 n][8]
//  skip : [m][256]  (row-major, feeds end_kernel)

typedef __hip_bfloat16 bf16;
typedef __attribute__((ext_vector_type(8))) short short8;
typedef __attribute__((ext_vector_type(4))) short short4v;
typedef __attribute__((ext_vector_type(4))) float f32x4;

__device__ __forceinline__ void g2l16(const void* g, void* l) {
  __builtin_amdgcn_global_load_lds(
      (const __attribute__((address_space(1))) unsigned int*)g,
      (__attribute__((address_space(3))) unsigned int*)l, 16, 0, 0);
}

#define VM4()   asm volatile("s_waitcnt vmcnt(4)"  ::: "memory")
#define VM5()   asm volatile("s_waitcnt vmcnt(5)"  ::: "memory")
#define VM0()   asm volatile("s_waitcnt vmcnt(0)"  ::: "memory")
#define LGKM0() asm volatile("s_waitcnt lgkmcnt(0)" ::: "memory")
#define SB0()   __builtin_amdgcn_sched_barrier(0)
#define BAR()   __builtin_amdgcn_s_barrier()

__device__ __forceinline__ float fsigmoid(float x) { return 1.f / (1.f + __expf(-x)); }
__device__ __forceinline__ float ftanh_(float x) { return 1.f - 2.f / (__expf(2.f * x) + 1.f); }
__device__ __forceinline__ float bf2f(unsigned short u) {
  unsigned x = ((unsigned)u) << 16; float f; __builtin_memcpy(&f, &x, 4); return f;
}
__device__ __forceinline__ short f2bf_s(float x) {
  bf16 v = __float2bfloat16(x); short s; __builtin_memcpy(&s, &v, 2); return s;
}

// ---------------------------------------------------------------------------
// GEMM1: x = [h(t-d);h(t);h(t+d);spect] @ Wstack^T ; acts = tanh(x1)*sig(x2)
// R19 structure + K-loop unrolled x2 with COMPILE-TIME slot pointers:
// each body's 8 ds_read addresses are loop-invariant (hoisted to VGPRs once),
// killing per-chunk VALU address recomputation. Sync per chunk identical to
// the proven template: stage(next); vmcnt(4); bar; reads; lgkm0; bar; MFMA.
// 1-D grid, xcd-major sibling-adjacent (4 y-slices share A via XCD L2).
// ---------------------------------------------------------------------------
__global__ __launch_bounds__(256, 4) void gemm1_kernel(
    const bf16* __restrict__ hpad, const bf16* __restrict__ spect,
    const bf16* __restrict__ wx,   // this layer: [44][4][512][8]
    const float* __restrict__ xb,  // [512] combined in_b + cond_b
    bf16* __restrict__ acts, int dil)
{
  // slot (shorts): A [4 kc][128 t][8]=4096, B1 [4][64 n][8]=2048, B2 2048
  __shared__ alignas(16) short lds[2 * 8192];    // 32 KB

  const int tid  = threadIdx.x;
  const int lane = tid & 63;
  const int wid  = tid >> 6;
  const int wm   = wid >> 1;          // 0..1
  const int wn   = wid & 1;           // 0..1

  const int id   = blockIdx.x;        // 2048 blocks
  const int xcd  = id & 7;
  const int seq  = id >> 3;
  const int tile = seq >> 2;          // 0..63
  const int y    = seq & 3;
  const int m0 = (xcd * 64 + tile) * 128;
  const int c0 = y * 64;              // tanh channel tile: 0/64/128/192
  const int b  = m0 >> 12;            // tile fully inside one batch
  const int t0 = m0 & (SEQT - 1);

  const f32x4 fzero = {0.f, 0.f, 0.f, 0.f};
  f32x4 acc1[4][2], acc2[4][2];
#pragma unroll
  for (int i = 0; i < 4; ++i)
#pragma unroll
    for (int j = 0; j < 2; ++j) { acc1[i][j] = fzero; acc2[i][j] = fzero; }

  const int tA  = tid & 127;
  const int ccA = tid >> 7;           // 0..1 -> stages cc=ccA, ccA+2
  const int nB  = tid & 63;
  const int kcB = tid >> 6;           // 0..3

  const bf16* pAh = hpad  + (((size_t)b * 32 + ccA) * TPAD + PADT + t0 + tA) * 8;
  const bf16* pAs = spect + (((size_t)b * 80 + ccA) * 4096 + t0 + tA) * 8;
  const bf16* pB1 = wx + ((size_t)(kcB * 512) + c0 + nB) * 8;
  const bf16* pB2 = pB1 + 2048;       // +256 cols (sigmoid class)
  const ptrdiff_t dil8 = (ptrdiff_t)dil * 8;

  auto stage = [&](int kt) {
    short* base = lds + (kt & 1) * 8192;
    const bf16* a0;
    ptrdiff_t astep;
    if (kt < 24) {
      const int tap = kt >> 3;                       // 0,1,2
      a0 = pAh + (ptrdiff_t)((kt & 7) * 4) * (TPAD * 8) + (ptrdiff_t)(tap - 1) * dil8;
      astep = (ptrdiff_t)2 * TPAD * 8;
    } else {
      a0 = pAs + (ptrdiff_t)(kt - 24) * 131072;      // 4*4096*8
      astep = (ptrdiff_t)2 * 4096 * 8;
    }
    const bf16* w1 = pB1 + (ptrdiff_t)kt * 16384;    // 4*512*8
    const bf16* w2 = pB2 + (ptrdiff_t)kt * 16384;
    g2l16(a0,         base + (ccA * 128 + tA) * 8);
    g2l16(a0 + astep, base + ((ccA + 2) * 128 + tA) * 8);
    g2l16(w1,         base + 4096 + (kcB * 64 + nB) * 8);
    g2l16(w2,         base + 6144 + (kcB * 64 + nB) * 8);
  };

  const int rl = lane & 15;
  const int kc = lane >> 4;           // 0..3

  // body: reads from compile-time slot pointer -> addresses loop-invariant
  auto body = [&](const short* cur) {
    short8 af[4], bfa[2], bfb[2];
#pragma unroll
    for (int f = 0; f < 4; ++f)
      af[f]  = *(const short8*)(cur + (kc * 128 + wm * 64 + f * 16 + rl) * 8);
#pragma unroll
    for (int j = 0; j < 2; ++j) {
      bfa[j] = *(const short8*)(cur + 4096 + (kc * 64 + wn * 32 + j * 16 + rl) * 8);
      bfb[j] = *(const short8*)(cur + 6144 + (kc * 64 + wn * 32 + j * 16 + rl) * 8);
    }
    LGKM0();
    SB0();
    BAR();                             // all reads of this slot retired
    __builtin_amdgcn_s_setprio(1);
#pragma unroll
    for (int i = 0; i < 4; ++i)
#pragma unroll
      for (int j = 0; j < 2; ++j) {
        acc1[i][j] = __builtin_amdgcn_mfma_f32_16x16x32_bf16(af[i], bfa[j], acc1[i][j], 0, 0, 0);
        acc2[i][j] = __builtin_amdgcn_mfma_f32_16x16x32_bf16(af[i], bfb[j], acc2[i][j], 0, 0, 0);
      }
    __builtin_amdgcn_s_setprio(0);
  };

  stage(0);                            // PROLOGUE
  for (int k2 = 0; k2 < 22; ++k2) {
    const int kt = 2 * k2;
    // even chunk (slot 0): kt+1 <= 43 always valid to stage
    stage(kt + 1); VM4();
    BAR();                             // slot 0 fully staged
    body(lds);
    // odd chunk (slot 1)
    if (kt + 2 < 44) { stage(kt + 2); VM4(); }
    else             { VM0(); }
    BAR();                             // slot 1 fully staged
    body(lds + 8192);
  }

  // ---- epilogue: gate -> LDS bounce [8 cc'][128 t][8] -> coalesced stores
  short* obuf = lds;                   // 16 KB (slot 0; last chunk used slot 1)
  const int rl2 = lane & 15;
  const int ro  = (lane >> 4) * 4;
#pragma unroll
  for (int i = 0; i < 4; ++i) {
#pragma unroll
    for (int j = 0; j < 2; ++j) {
      const int lc = wn * 32 + j * 16 + rl2;         // local tanh ch 0..63
      const float bx1 = xb[c0 + lc];
      const float bx2 = xb[c0 + lc + 256];
#pragma unroll
      for (int r = 0; r < 4; ++r) {
        const int t = wm * 64 + i * 16 + ro + r;     // 0..127
        const float x1 = acc1[i][j][r] + bx1;
        const float x2 = acc2[i][j][r] + bx2;
        obuf[((lc >> 3) * 128 + t) * 8 + (lc & 7)] = f2bf_s(ftanh_(x1) * fsigmoid(x2));
      }
    }
  }
  __syncthreads();
  const int tt = tid & 127;
  const int c2 = tid >> 7;            // 0..1
  short* ag = (short*)acts;
#pragma unroll
  for (int q = 0; q < 4; ++q) {
    const int ccp = c2 * 4 + q;       // 0..7
    const short8 v = *(const short8*)(obuf + (ccp * 128 + tt) * 8);
    *(short8*)(ag + ((size_t)(b * 32 + (c0 >> 3) + ccp) * 4096 + t0 + tt) * 8) = v;
  }
}

// ---------------------------------------------------------------------------
// GEMM2: rs = acts @ Wr^T (+rb); n-half 0 -> h += rs ; half 1 -> skip += rs
// R13 structure + R15 coalesced epilogues + xcd-major sibling-adjacent grid.
// ---------------------------------------------------------------------------
__global__ __launch_bounds__(256, 3) void gemm2_kernel(
    const bf16* __restrict__ acts, const bf16* __restrict__ wr,  // [8][4][512][8]
    const float* __restrict__ rb, bf16* __restrict__ hpad,
    bf16* __restrict__ skip, const int first)
{
  // slot (shorts): A [4 kc][64 t][8]=2048, B [4 kc][256 n][8]=8192
  __shared__ alignas(16) short lds[2 * 10240];   // 40 KB (obuf needs 32 KB)

  const int tid  = threadIdx.x;
  const int lane = tid & 63;
  const int wid  = tid >> 6;
  const int wm   = wid >> 1;          // 0..1
  const int wn   = wid & 1;           // 0..1

  const int id   = blockIdx.x;        // 2048 blocks
  const int xcd  = id & 7;
  const int seq  = id >> 3;
  const int tile = seq >> 1;          // 0..127
  const int half = seq & 1;
  const int m0 = (xcd * 128 + tile) * 64;
  const int n0 = half * 256;          // 0 (h-update) or 256 (skip)
  const int b  = m0 >> 12;
  const int t0 = m0 & (SEQT - 1);

  const f32x4 fzero = {0.f, 0.f, 0.f, 0.f};
  f32x4 acc[2][8];
#pragma unroll
  for (int i = 0; i < 2; ++i)
#pragma unroll
    for (int j = 0; j < 8; ++j) acc[i][j] = fzero;

  const int tA  = tid & 63;
  const int ccA = tid >> 6;           // 0..3

  const bf16* pA = acts + (((size_t)b * 32 + ccA) * 4096 + t0 + tA) * 8;
  const bf16* pB = wr + ((size_t)n0 + tid) * 8;    // col n0+tid, all 4 kc

  auto stage = [&](int kt) {
    short* base = lds + (kt & 1) * 10240;
    const bf16* a0 = pA + (ptrdiff_t)kt * 131072;  // 4*4096*8
    const bf16* w0 = pB + (ptrdiff_t)kt * 16384;   // 4*512*8
    g2l16(a0, base + (ccA * 64 + tA) * 8);
#pragma unroll
    for (int kcq = 0; kcq < 4; ++kcq)
      g2l16(w0 + kcq * 4096, base + 2048 + (kcq * 256 + tid) * 8);
  };

  const int rl = lane & 15;
  const int kc = lane >> 4;

  stage(0);                            // PROLOGUE
  for (int kt = 0; kt < 8; ++kt) {
    if (kt < 7) { stage(kt + 1); VM5(); }
    else        { VM0(); }
    BAR();

    const short* cur = lds + (kt & 1) * 10240;
    short8 af[2], bfr[8];
#pragma unroll
    for (int f = 0; f < 2; ++f)
      af[f] = *(const short8*)(cur + (kc * 64 + wm * 32 + f * 16 + rl) * 8);
#pragma unroll
    for (int j = 0; j < 8; ++j)
      bfr[j] = *(const short8*)(cur + 2048 + (kc * 256 + wn * 128 + j * 16 + rl) * 8);
    LGKM0();
    SB0();
    BAR();
    __builtin_amdgcn_s_setprio(1);
#pragma unroll
    for (int i = 0; i < 2; ++i)
#pragma unroll
      for (int j = 0; j < 8; ++j)
        acc[i][j] = __builtin_amdgcn_mfma_f32_16x16x32_bf16(af[i], bfr[j], acc[i][j], 0, 0, 0);
    __builtin_amdgcn_s_setprio(0);
  }

  // ---- epilogue: rs+bias -> LDS bounce -> coalesced RMW
  short* obuf = lds;
  const int rl2 = lane & 15;
  const int ro  = (lane >> 4) * 4;
  if (n0 == 0) {
    // h-update: obuf NC8 [32 cc][64 t][8] = 32 KB
#pragma unroll
    for (int i = 0; i < 2; ++i) {
#pragma unroll
      for (int j = 0; j < 8; ++j) {
        const int n = wn * 128 + j * 16 + rl2;       // 0..255
        const float bias = rb[n];
#pragma unroll
        for (int r = 0; r < 4; ++r) {
          const int t = wm * 32 + i * 16 + ro + r;
          obuf[((n >> 3) * 64 + t) * 8 + (n & 7)] = f2bf_s(acc[i][j][r] + bias);
        }
      }
    }
    __syncthreads();
    const int tt = tid & 63;
    const int c4 = tid >> 6;
    short* hg = (short*)hpad;
#pragma unroll
    for (int q = 0; q < 8; ++q) {
      const int cc = c4 * 8 + q;                     // 0..31
      const size_t gi = (((size_t)b * 32 + cc) * TPAD + PADT + t0 + tt) * 8;
      short8 hv = *(const short8*)(hg + gi);
      const short8 rv = *(const short8*)(obuf + (cc * 64 + tt) * 8);
      short8 ov;
#pragma unroll
      for (int w = 0; w < 8; ++w)
        ov[w] = f2bf_s(bf2f((unsigned short)hv[w]) + bf2f((unsigned short)rv[w]));
      *(short8*)(hg + gi) = ov;
    }
  } else {
    // skip: obuf row-major [64 t][256 n] = 32 KB
#pragma unroll
    for (int i = 0; i < 2; ++i) {
#pragma unroll
      for (int j = 0; j < 8; ++j) {
        const int n = wn * 128 + j * 16 + rl2;       // 0..255
        const float bias = rb[256 + n];
#pragma unroll
        for (int r = 0; r < 4; ++r) {
          const int t = wm * 32 + i * 16 + ro + r;
          obuf[t * 256 + n] = f2bf_s(acc[i][j][r] + bias);
        }
      }
    }
    __syncthreads();
    short* sg = (short*)skip;
#pragma unroll
    for (int q = 0; q < 8; ++q) {
      const int idx = q * 256 + tid;                 // 0..2047 chunks
      const int t  = idx >> 5;
      const int nc = idx & 31;
      const size_t gi = ((size_t)(b * SEQT + t0 + t)) * NCH + nc * 8;
      const short8 rv = *(const short8*)(obuf + t * 256 + nc * 8);
      if (first) {
        *(short8*)(sg + gi) = rv;
      } else {
        short8 sv = *(const short8*)(sg + gi);
        short8 ov;
#pragma unroll
        for (int w = 0; w < 8; ++w)
          ov[w] = f2bf_s(bf2f((unsigned short)sv[w]) + bf2f((unsigned short)rv[w]));
        *(short8*)(sg + gi) = ov;
      }
    }
  }
}

// ---------------------------------------------------------------------------
// aux kernels
// ---------------------------------------------------------------------------
__global__ void start_kernel(const float* __restrict__ audio, const float* __restrict__ sw,
                             const float* __restrict__ sb, bf16* __restrict__ hpad)
{
  const int idx = blockIdx.x * 256 + threadIdx.x;   // < 16777216
  const int w  = idx & 7;
  const int t  = (idx >> 3) & 4095;
  const int cc = (idx >> 15) & 31;
  const int b  = idx >> 20;
  const int c  = cc * 8 + w;
  const float* a = audio + ((size_t)(b * SEQT + t)) * 4;
  float v = sb[c] + a[0] * sw[c] + a[1] * sw[256 + c] + a[2] * sw[512 + c] + a[3] * sw[768 + c];
  hpad[(((size_t)b * 32 + cc) * TPAD + PADT + t) * 8 + w] = __float2bfloat16(v);
}

// cvt_spect: tiled LDS-bounce transpose. Block = (b, 8 t, 128 c).
__global__ void cvt_spect_kernel(const float* __restrict__ s, bf16* __restrict__ d)
{
  __shared__ short tile[1024];        // [8 t][128 c] bf16
  const int bid  = blockIdx.x;        // 40960 = 16 b * 512 t-tiles * 5 c-tiles
  const int ct   = bid % 5;
  const int rest = bid / 5;
  const int tt   = rest & 511;
  const int b    = rest >> 9;
  const int c0   = ct * 128;
  const int t0   = tt * 8;
  const int tid  = threadIdx.x;

  const int cl = tid & 31;            // float4 index in row
  const int tr = tid >> 5;            // 0..7
  const float4 v = *(const float4*)(s + ((size_t)(b * SEQT + t0 + tr)) * NMEL + c0 + cl * 4);
  short* tp = tile + tr * 128 + cl * 4;
  tp[0] = f2bf_s(v.x); tp[1] = f2bf_s(v.y); tp[2] = f2bf_s(v.z); tp[3] = f2bf_s(v.w);
  __syncthreads();

  const int half = tid & 1;
  const int tr2  = (tid >> 1) & 7;
  const int ccl  = tid >> 4;          // 0..15
  const short4v o = *(const short4v*)(tile + tr2 * 128 + ccl * 8 + half * 4);
  *(short4v*)((short*)d + (((size_t)b * 80 + (c0 >> 3) + ccl) * 4096 + t0 + tr2) * 8 + half * 4) = o;
}

__global__ void prep_wx_kernel(const float* __restrict__ in_w, const float* __restrict__ cond_w,
                               bf16* __restrict__ wx)
{
  const size_t idx = (size_t)blockIdx.x * 256 + threadIdx.x;
  if (idx >= (size_t)LAYERS * 44 * 4 * 512 * 8) return;
  const int w   = (int)(idx & 7);
  const int n   = (int)((idx >> 3) & 511);
  const int kc  = (int)((idx >> 12) & 3);
  const unsigned ktp = (unsigned)(idx >> 14);   // i*44 + kt
  const int i  = ktp / 44;
  const int kt = ktp % 44;
  const int k  = kt * 32 + kc * 8 + w;
  float v;
  if (k < 768) {
    const int tap = k >> 8;
    const int c   = k & 255;
    v = in_w[(size_t)(((i * 3 + tap) << 8) + c) * 512 + n];
  } else {
    v = cond_w[((size_t)i * NMEL + (k - 768)) * 512 + n];
  }
  wx[idx] = __float2bfloat16(v);
}

__global__ void prep_wr_kernel(const float* __restrict__ rs_w, const float* __restrict__ rs_w_last,
                               bf16* __restrict__ wr)
{
  const int idx = blockIdx.x * 256 + threadIdx.x;   // < 1048576
  const int w  = idx & 7;
  const int n  = (idx >> 3) & 511;
  const int kc = (idx >> 12) & 3;
  const int kt = (idx >> 14) & 7;
  const int i  = idx >> 17;
  const int k  = kt * 32 + kc * 8 + w;              // [0,256)
  float v;
  if (i < LAYERS - 1) v = rs_w[(size_t)((i << 8) + k) * 512 + n];
  else                v = (n >= 256) ? rs_w_last[(k << 8) + (n - 256)] : 0.f;
  wr[idx] = __float2bfloat16(v);
}

__global__ void prep_bias_kernel(const float* __restrict__ in_b, const float* __restrict__ cond_b,
                                 const float* __restrict__ rs_b, const float* __restrict__ rs_b_last,
                                 float* __restrict__ xb, float* __restrict__ rb)
{
  const int idx = blockIdx.x * 256 + threadIdx.x;   // < 4096
  if (idx >= LAYERS * 512) return;
  const int i = idx >> 9;
  const int n = idx & 511;
  xb[idx] = in_b[idx] + cond_b[idx];
  rb[idx] = (i < LAYERS - 1) ? rs_b[idx] : ((n >= 256) ? rs_b_last[n - 256] : 0.f);
}

__global__ void end_kernel(const bf16* __restrict__ skip, const float* __restrict__ ew,
                           const float* __restrict__ eb, float* __restrict__ out)
{
  const int idx = blockIdx.x * 256 + threadIdx.x;   // < 524288
  const int m = idx >> 3;
  const int j = idx & 7;
  const bf16* srow = skip + (size_t)m * NCH;
  float s = eb[j];
#pragma unroll 4
  for (int c8 = 0; c8 < NCH / 8; ++c8) {
    short8 v = *(const short8*)(srow + c8 * 8);
#pragma unroll
    for (int w = 0; w < 8; ++w)
      s += bf2f((unsigned short)v[w]) * ew[(c8 * 8 + w) * 8 + j];
  }
  out[idx] = s;
}

// ---------------------------------------------------------------------------
extern "C" void kernel_launch(void* const* d_in, const int* in_sizes, int n_in,
                              void* d_out, int out_size, void* d_ws, size_t ws_size,
                              hipStream_t stream)
{
  const float* audio     = (const float*)d_in[0];
  const float* spect     = (const float*)d_in[1];
  const float* start_w   = (const float*)d_in[2];
  const float* start_b   = (const float*)d_in[3];
  const float* in_w      = (const float*)d_in[4];
  const float* in_b      = (const float*)d_in[5];
  const float* cond_w    = (const float*)d_in[6];
  const float* cond_b    = (const float*)d_in[7];
  const float* rs_w      = (const float*)d_in[8];
  const float* rs_b      = (const float*)d_in[9];
  const float* rs_w_last = (const float*)d_in[10];
  const float* rs_b_last = (const float*)d_in[11];
  const float* end_w     = (const float*)d_in[12];
  const float* end_b     = (const float*)d_in[13];
  float* out = (float*)d_out;

  char* p = (char*)d_ws;
  bf16* spect_bf = (bf16*)p;  p += (size_t)BTROWS * NMEL * 2;          // 83.9 MB
  bf16* hpad     = (bf16*)p;  p += (size_t)NBATCH * 32 * TPAD * 8 * 2; // 35.7 MB
  bf16* actsb    = (bf16*)p;  p += (size_t)BTROWS * NCH * 2;           // 33.6 MB
  bf16* skip     = (bf16*)p;  p += (size_t)BTROWS * NCH * 2;           // 33.6 MB
  bf16* wx       = (bf16*)p;  p += (size_t)LAYERS * 512 * KX * 2;      // 11.5 MB
  bf16* wr       = (bf16*)p;  p += (size_t)LAYERS * 512 * 256 * 2;     //  2.1 MB
  float* xb      = (float*)p; p += (size_t)LAYERS * 512 * 4;
  float* rb      = (float*)p; p += (size_t)LAYERS * 512 * 4;
  if ((size_t)(p - (char*)d_ws) > ws_size) return;  // insufficient workspace

  hipMemsetAsync(hpad, 0, (size_t)NBATCH * 32 * TPAD * 8 * 2, stream);
  prep_wx_kernel<<<(LAYERS * 512 * KX + 255) / 256, 256, 0, stream>>>(in_w, cond_w, wx);
  prep_wr_kernel<<<(LAYERS * 512 * 256) / 256, 256, 0, stream>>>(rs_w, rs_w_last, wr);
  prep_bias_kernel<<<16, 256, 0, stream>>>(in_b, cond_b, rs_b, rs_b_last, xb, rb);
  cvt_spect_kernel<<<40960, 256, 0, stream>>>(spect, spect_bf);
  start_kernel<<<(BTROWS * NCH) / 256, 256, 0, stream>>>(audio, start_w, start_b, hpad);

  for (int i = 0; i < LAYERS; ++i) {
    gemm1_kernel<<<2048, 256, 0, stream>>>(hpad, spect_bf, wx + (size_t)i * 44 * 4 * 512 * 8,
                                           xb + i * 512, actsb, 1 << i);
    gemm2_kernel<<<2048, 256, 0, stream>>>(actsb, wr + (size_t)i * 8 * 4 * 512 * 8,
                                           rb + i * 512, hpad, skip, i == 0 ? 1 : 0);
  }
  end_kernel<<<(BTROWS * 8) / 256, 256, 0, stream>>>(skip, end_w, end_b, out);
}